// Round 8
// baseline (320.542 us; speedup 1.0000x reference)
//
#include <hip/hip_runtime.h>
#include <math.h>

#define BB 16
#define LL 1024
#define DM 6
#define NST 32
#define DCONVK 16
#define NCLS 4

#define NBLK 256
#define BT   1024
#define PCH  64              // pre: positions per block
#define HALO 15
#define PROWS (PCH + HALO)   // 79
#define SNC 16               // scan chunks per 512-thr unit
#define SCS 64               // chunk length

// smem layout (float offsets)
#define O_U    0        // union: s_pp(3792) / s_raw(79*49=3871) / s_bc(64*65=4160)
#define O_IPW  4160     // 576
#define O_NW   4736     // 8
#define O_CW   4744     // 768
#define O_CB   5512     // 48
#define O_XPW  5560     // 3120
#define O_DTW  8680     // 48
#define O_DTB  8728     // 48
#define O_OPW  8776     // 288
#define O_SU   9064     // 79*7 -> 560
#define O_XST  9624     // 48*64 = 3072
#define O_DLT  12696    // 64
#define SMEM_F 12768    // ~51 KB

__device__ __forceinline__ float softplus_f(float x) {
    return fmaxf(x, 0.f) + log1pf(expf(-fabsf(x)));
}
__device__ __forceinline__ float silu_f(float x) {
    return x / (1.f + __expf(-x));
}

__device__ __forceinline__ void gbar(unsigned* cnt, unsigned target) {
    __syncthreads();
    if (threadIdx.x == 0) {
        __threadfence();
        __hip_atomic_fetch_add(cnt, 1u, __ATOMIC_RELEASE, __HIP_MEMORY_SCOPE_AGENT);
        for (int it = 0; it < 10000000; ++it) {
            if (__hip_atomic_load(cnt, __ATOMIC_ACQUIRE, __HIP_MEMORY_SCOPE_AGENT) >= target)
                break;
            __builtin_amdgcn_s_sleep(2);
        }
        __threadfence();
    }
    __syncthreads();
}

// ---- pre phase: [rmsnorm | proj0+res+rmsnorm] -> in_proj -> conv+silu -> x_proj -> delta
template<int MODE>
__device__ void pre_block(
    int b, int l0,
    const float* __restrict__ hin, const float* __restrict__ ygT_in,
    const float* __restrict__ opw, const float* __restrict__ ipw,
    const float* __restrict__ nw,  const float* __restrict__ cw,
    const float* __restrict__ cb,  const float* __restrict__ xpw,
    const float* __restrict__ dtw, const float* __restrict__ dtb,
    float* __restrict__ xT, float* __restrict__ zT, float* __restrict__ dT,
    float* __restrict__ Bi, float* __restrict__ Ci, float* sm)
{
    const int tid = threadIdx.x;
    float* s_ipw = sm + O_IPW;  float* s_nw  = sm + O_NW;
    float* s_cw  = sm + O_CW;   float* s_cb  = sm + O_CB;
    float* s_xpw = sm + O_XPW;  float* s_dtw = sm + O_DTW;
    float* s_dtb = sm + O_DTB;  float* s_opw = sm + O_OPW;
    float* s_u   = sm + O_SU;   float* s_xsT = sm + O_XST;
    float* s_dlt = sm + O_DLT;
    float* s_pp  = sm + O_U;    float* s_raw = sm + O_U;  float* s_bc = sm + O_U;

    // weight staging
    for (int i = tid; i < 576; i += BT) s_ipw[i] = ipw[i];
    if (tid < 6) s_nw[tid] = nw[tid];
    for (int i = tid; i < 768; i += BT) s_cw[i] = cw[i];
    if (tid < 48) s_cb[tid] = cb[tid];
    for (int i = tid; i < 3120; i += BT) s_xpw[i] = xpw[i];
    if (tid < 48) { s_dtw[tid] = dtw[tid]; s_dtb[tid] = dtb[tid]; }
    if (MODE == 1) for (int i = tid; i < 288; i += BT) s_opw[i] = opw[i];
    __syncthreads();

    // phase 0: normalized input rows [l0-15, l0+64)
    if (MODE == 0) {
        if (tid < PROWS) {
            int l = l0 - HALO + tid;
            float u[DM];
            if (l >= 0) {
                float ss = 0.f;
                const float* hp = hin + ((size_t)b*LL + l)*DM;
                #pragma unroll
                for (int d = 0; d < DM; ++d) { u[d] = hp[d]; ss += u[d]*u[d]; }
                float sc = rsqrtf(ss * (1.f/DM) + 1e-5f);
                #pragma unroll
                for (int d = 0; d < DM; ++d) u[d] *= sc * s_nw[d];
            } else {
                #pragma unroll
                for (int d = 0; d < DM; ++d) u[d] = 0.f;
            }
            #pragma unroll
            for (int d = 0; d < DM; ++d) s_u[tid*7+d] = u[d];
        }
        __syncthreads();
    } else {
        const int g = tid >> 7, t = tid & 127;   // 8 e-groups x rows
        if (t < PROWS) {
            int l = l0 - HALO + t;
            float pacc[DM] = {0,0,0,0,0,0};
            if (l >= 0) {
                for (int e = g*6; e < g*6 + 6; ++e) {
                    float v = ygT_in[((size_t)b*48 + e)*LL + l];
                    #pragma unroll
                    for (int d = 0; d < DM; ++d) pacc[d] += v * s_opw[e*DM+d];
                }
            }
            #pragma unroll
            for (int d = 0; d < DM; ++d) s_pp[(t*8+g)*DM+d] = pacc[d];
        }
        __syncthreads();
        if (tid < PROWS) {
            int l = l0 - HALO + tid;
            float u[DM];
            if (l >= 0) {
                const float* xr = hin + ((size_t)b*LL + l)*DM;
                float ss = 0.f;
                #pragma unroll
                for (int d = 0; d < DM; ++d) {
                    float hv = xr[d];
                    #pragma unroll
                    for (int g2 = 0; g2 < 8; ++g2) hv += s_pp[(tid*8+g2)*DM+d];
                    u[d] = hv; ss += hv*hv;
                }
                float sc = rsqrtf(ss * (1.f/DM) + 1e-5f);
                #pragma unroll
                for (int d = 0; d < DM; ++d) u[d] *= sc * s_nw[d];
            } else {
                #pragma unroll
                for (int d = 0; d < DM; ++d) u[d] = 0.f;
            }
            #pragma unroll
            for (int d = 0; d < DM; ++d) s_u[tid*7+d] = u[d];
        }
        __syncthreads();
    }

    // phase 1: in_proj (96 x 79); z-half silu'd to global (overwrites s_pp region)
    for (int i = tid; i < 96*PROWS; i += BT) {
        int j = i / PROWS, t = i - j*PROWS;
        float acc = 0.f;
        #pragma unroll
        for (int d = 0; d < DM; ++d) acc += s_u[t*7+d]*s_ipw[d*96+j];
        if (j < 48) s_raw[t*49+j] = acc;
        else if (t >= HALO)
            zT[((size_t)b*48 + (j-48))*LL + (l0 - HALO + t)] = silu_f(acc);
    }
    __syncthreads();

    // phase 2: causal depthwise conv (K=16) + silu
    for (int o = tid; o < 48*PCH; o += BT) {
        int c = o >> 6, p = o & 63;
        float acc = s_cb[c];
        #pragma unroll
        for (int k = 0; k < DCONVK; ++k)
            acc += s_raw[(p+k)*49 + c] * s_cw[c*DCONVK + k];
        float v = silu_f(acc);
        s_xsT[c*PCH + p] = v;
        xT[((size_t)b*48 + c)*LL + l0 + p] = v;
    }
    __syncthreads();

    // phase 3: x_proj (64 B/C cols x 16 pos-groups); dlt on tid<16
    {
        const int j = tid >> 4, g = tid & 15;
        float a0=0,a1=0,a2=0,a3=0;
        for (int e = 0; e < 48; ++e) {
            float4 xv = *(const float4*)&s_xsT[e*PCH + 4*g];
            float w = s_xpw[e*65 + 1 + j];
            a0 = fmaf(xv.x, w, a0); a1 = fmaf(xv.y, w, a1);
            a2 = fmaf(xv.z, w, a2); a3 = fmaf(xv.w, w, a3);
        }
        s_bc[j*65 + 4*g+0] = a0; s_bc[j*65 + 4*g+1] = a1;
        s_bc[j*65 + 4*g+2] = a2; s_bc[j*65 + 4*g+3] = a3;
    }
    if (tid < 16) {
        float a0=0,a1=0,a2=0,a3=0;
        for (int e = 0; e < 48; ++e) {
            float4 xv = *(const float4*)&s_xsT[e*PCH + 4*tid];
            float w = s_xpw[e*65];
            a0 = fmaf(xv.x, w, a0); a1 = fmaf(xv.y, w, a1);
            a2 = fmaf(xv.z, w, a2); a3 = fmaf(xv.w, w, a3);
        }
        s_dlt[4*tid+0] = a0; s_dlt[4*tid+1] = a1;
        s_dlt[4*tid+2] = a2; s_dlt[4*tid+3] = a3;
    }
    __syncthreads();

    // phase 3b: B/C interleaved write (coalesced)
    for (int o = tid; o < 2*PCH*32; o += BT) {
        int which = o >> 11;
        int l = (o >> 5) & 63, n = o & 31;
        float v = s_bc[(which*32 + n)*65 + l];
        float* dst = which ? Ci : Bi;
        dst[((size_t)b*LL + l0 + l)*32 + n] = v;
    }

    // phase 4: delta = softplus
    for (int o = tid; o < 48*PCH; o += BT) {
        int e = o >> 6, p = o & 63;
        float xv = s_dlt[p]*s_dtw[e] + s_dtb[e];
        dT[((size_t)b*48 + e)*LL + l0 + p] = softplus_f(xv);
    }
}

// ---- scan unit: 512-thread sub-block, unit u = (b,e); wr gates global stores
__device__ void scan_unit(
    int u, int wr, int sub,
    const float* __restrict__ dT, const float* __restrict__ xT,
    const float* __restrict__ zT, const float* __restrict__ Bi,
    const float* __restrict__ Ci, const float* __restrict__ A_log,
    const float* __restrict__ Dw, float* __restrict__ ygT, float* sm)
{
    const int tid = threadIdx.x & 511;
    const int lane = threadIdx.x & 63;
    const int ch = lane >> 5, n = lane & 31;
    const int c = ((tid >> 6) << 1) | ch;       // chunk 0..15
    const int b = u / 48, e = u % 48;

    float2* sPH  = (float2*)(sm + sub*4096);
    float2* sACa = (float2*)(sm + sub*4096 + 1024);
    float*  sYL  = sm + sub*4096 + 2048;
    float*  sS   = sm + sub*4096 + 3072;

    const float Ac = -__expf(A_log[e*NST + n]);
    const float Dc = Dw[e];

    const size_t eb = ((size_t)b*48 + e)*LL + c*SCS;
    const float4* dp = (const float4*)(dT + eb);
    const float4* xp = (const float4*)(xT + eb);
    const float*  bp = Bi + ((size_t)b*LL + c*SCS)*32 + n;
    const float*  cp = Ci + ((size_t)b*LL + c*SCS)*32 + n;

    float h = 0.f, S = 0.f;

    // phase A
    #pragma unroll
    for (int q = 0; q < SCS/4; ++q) {
        float4 d4 = dp[q], x4 = xp[q];
        float b0 = bp[(4*q+0)*32], b1 = bp[(4*q+1)*32];
        float b2 = bp[(4*q+2)*32], b3 = bp[(4*q+3)*32];
        float c0 = cp[(4*q+0)*32], c1 = cp[(4*q+1)*32];
        float c2 = cp[(4*q+2)*32], c3 = cp[(4*q+3)*32];
        float p0, p1, p2, p3;
        h = fmaf(__expf(d4.x*Ac), h, d4.x*x4.x*b0); p0 = h*c0;
        h = fmaf(__expf(d4.y*Ac), h, d4.y*x4.y*b1); p1 = h*c1;
        h = fmaf(__expf(d4.z*Ac), h, d4.z*x4.z*b2); p2 = h*c2;
        h = fmaf(__expf(d4.w*Ac), h, d4.w*x4.w*b3); p3 = h*c3;
        float s0 = S + d4.x, s1 = s0 + d4.y, s2 = s1 + d4.z, s3 = s2 + d4.w;
        S = s3;
        if (n == 0) *(float4*)&sS[c*SCS + 4*q] = make_float4(s0, s1, s2, s3);
        float q0 = p0 + __shfl_xor(p0, 16);
        float q1 = p1 + __shfl_xor(p1, 16);
        float q2 = p2 + __shfl_xor(p2, 16);
        float q3 = p3 + __shfl_xor(p3, 16);
        float m01 = (n & 16) ? q1 : q0;
        float m23 = (n & 16) ? q3 : q2;
        m01 += __shfl_xor(m01, 8);
        m23 += __shfl_xor(m23, 8);
        float mm = (n & 8) ? m23 : m01;
        mm += __shfl_xor(mm, 4);
        mm += __shfl_xor(mm, 2);
        mm += __shfl_xor(mm, 1);
        if ((n & 7) == 0) {
            int vidx = ((n >> 4) & 1) | (((n >> 3) & 1) << 1);
            float xv = (vidx & 2) ? ((vidx & 1) ? x4.w : x4.z)
                                  : ((vidx & 1) ? x4.y : x4.x);
            sYL[c*SCS + 4*q + vidx] = fmaf(Dc, xv, mm);
        }
    }
    sPH[c*32 + n] = make_float2(__expf(Ac*S), h);
    __syncthreads();

    // phase B: carry scan (first 32 threads of each sub)
    if (tid < 32) {
        float2 v[SNC];
        #pragma unroll
        for (int k = 0; k < SNC; ++k) v[k] = sPH[k*32 + tid];
        float acc = 0.f;
        #pragma unroll
        for (int k = 0; k < SNC; ++k) {
            sACa[k*32 + tid] = make_float2(Ac, acc);
            acc = fmaf(v[k].x, acc, v[k].y);
        }
    }
    __syncthreads();

    // phase C: thread=(chunk,t), 2 rounds; correction + gate
    #pragma unroll
    for (int r = 0; r < 2; ++r) {
        const int c2 = (tid >> 6) + 8*r;
        const int t = lane;
        const float St = sS[c2*SCS + t];
        const float yl = sYL[c2*SCS + t];
        const float4* cpt = (const float4*)(Ci + ((size_t)b*LL + c2*SCS + t)*32);
        float corr = 0.f;
        #pragma unroll
        for (int k = 0; k < 8; ++k) {
            float4 cv = cpt[k];
            float4 w0 = *(const float4*)&sACa[c2*32 + 4*k];
            float4 w1 = *(const float4*)&sACa[c2*32 + 4*k + 2];
            corr = fmaf(cv.x * __expf(w0.x*St), w0.y, corr);
            corr = fmaf(cv.y * __expf(w0.z*St), w0.w, corr);
            corr = fmaf(cv.z * __expf(w1.x*St), w1.y, corr);
            corr = fmaf(cv.w * __expf(w1.z*St), w1.w, corr);
        }
        if (wr) {
            const size_t o = ((size_t)b*48 + e)*LL + c2*SCS + t;
            ygT[o] = (yl + corr) * zT[o];
        }
    }
}

__global__ void init_kernel(unsigned* cnt) {
    if (threadIdx.x == 0) *cnt = 0u;
}

__global__ __launch_bounds__(BT, 4) void mega_kernel(
    const float* __restrict__ x,   const float* __restrict__ ipw,
    const float* __restrict__ cw,  const float* __restrict__ cb,
    const float* __restrict__ xpw, const float* __restrict__ dtw,
    const float* __restrict__ dtb, const float* __restrict__ A_log,
    const float* __restrict__ Dw,  const float* __restrict__ nw,
    const float* __restrict__ opw, const float* __restrict__ fcw,
    const float* __restrict__ fcb, const float* __restrict__ clw,
    const float* __restrict__ clb, const float* __restrict__ rgw,
    const float* __restrict__ rgb,
    float* __restrict__ xT, float* __restrict__ zT, float* __restrict__ dT,
    float* __restrict__ Bi, float* __restrict__ Ci, float* __restrict__ ygT,
    float* __restrict__ out, unsigned* cnt)
{
    __shared__ float sm[SMEM_F];
    const int blk = blockIdx.x;
    const int tid = threadIdx.x;
    const int b_pre = blk >> 4, l0 = (blk & 15) * PCH;
    const int sub = tid >> 9;

    // ---- layer 0 ----
    pre_block<0>(b_pre, l0, x, nullptr, nullptr, ipw, nw, cw, cb, xpw, dtw, dtb,
                 xT, zT, dT, Bi, Ci, sm);
    gbar(cnt, 1*NBLK);
    for (int r = 0; r < 2; ++r) {
        int u  = (r == 0) ? (blk*3 + sub) : (blk*3 + 2);
        int wr = (r == 0) ? 1 : (sub == 0);
        scan_unit(u, wr, sub, dT, xT, zT, Bi, Ci, A_log, Dw, ygT, sm);
        __syncthreads();
    }
    gbar(cnt, 2*NBLK);

    // ---- layer 1 ----
    pre_block<1>(b_pre, l0, x, ygT, opw, ipw + 576, nw + 6, cw + 768, cb + 48,
                 xpw + 3120, dtw + 48, dtb + 48, xT, zT, dT, Bi, Ci, sm);
    gbar(cnt, 3*NBLK);
    for (int r = 0; r < 2; ++r) {
        int u  = (r == 0) ? (blk*3 + sub) : (blk*3 + 2);
        int wr = (r == 0) ? 1 : (sub == 0);
        scan_unit(u, wr, sub, dT, xT, zT, Bi, Ci, A_log + 1536, Dw + 48, ygT, sm);
        __syncthreads();
    }
    gbar(cnt, 4*NBLK);

    // ---- head (block 0) ----
    if (blk == 0) {
        float* s_h = sm;
        float* s_f = sm + 800;
        const int b = tid >> 6, j = tid & 63;
        if (j < 48) s_h[b*48+j] = ygT[((size_t)b*48 + j)*LL + (LL-1)];
        __syncthreads();
        if (j < 48) {
            float acc = fcb[j];
            for (int k = 0; k < 48; ++k) acc += s_h[b*48+k]*fcw[k*48+j];
            s_f[b*48+j] = fmaxf(acc, 0.f);
        }
        __syncthreads();
        if (j < NCLS) {
            float acc = clb[j];
            for (int k = 0; k < 48; ++k) acc += s_f[b*48+k]*clw[k*NCLS+j];
            out[b*NCLS + j] = acc;
        }
        if (j == NCLS) {
            float acc = rgb[0];
            for (int k = 0; k < 48; ++k) acc += s_f[b*48+k]*rgw[k];
            out[BB*NCLS + b] = acc;
        }
    }
}

extern "C" void kernel_launch(void* const* d_in, const int* in_sizes, int n_in,
                              void* d_out, int out_size, void* d_ws, size_t ws_size,
                              hipStream_t stream)
{
    const float* x     = (const float*)d_in[0];
    const float* ipw   = (const float*)d_in[1];
    const float* cw    = (const float*)d_in[2];
    const float* cb    = (const float*)d_in[3];
    const float* xpw   = (const float*)d_in[4];
    const float* dtw   = (const float*)d_in[5];
    const float* dtb   = (const float*)d_in[6];
    const float* A_log = (const float*)d_in[7];
    const float* Dw    = (const float*)d_in[8];
    const float* nw    = (const float*)d_in[9];
    const float* opw   = (const float*)d_in[10];
    const float* fcw   = (const float*)d_in[11];
    const float* fcb   = (const float*)d_in[12];
    const float* clw   = (const float*)d_in[13];
    const float* clb   = (const float*)d_in[14];
    const float* rgw   = (const float*)d_in[15];
    const float* rgb   = (const float*)d_in[16];
    float* out = (float*)d_out;

    float* ws = (float*)d_ws;
    const size_t BL = (size_t)BB*LL;
    float* xT  = ws;
    float* zT  = xT  + BL*48;
    float* dT  = zT  + BL*48;
    float* Bi  = dT  + BL*48;
    float* Ci  = Bi  + BL*32;
    float* ygT = Ci  + BL*32;
    unsigned* cnt = (unsigned*)(ws + (size_t)8*1024*1024);  // 32 MB offset, past arrays

    init_kernel<<<dim3(1), dim3(64), 0, stream>>>(cnt);
    mega_kernel<<<dim3(NBLK), dim3(BT), 0, stream>>>(
        x, ipw, cw, cb, xpw, dtw, dtb, A_log, Dw, nw, opw,
        fcw, fcb, clw, clb, rgw, rgb,
        xT, zT, dT, Bi, Ci, ygT, out, cnt);
}

// Round 9
// 309.019 us; speedup vs baseline: 1.0373x; 1.0373x over previous
//
#include <hip/hip_runtime.h>
#include <math.h>

#define BB 16
#define LL 1024
#define DM 6
#define NST 32
#define DCONVK 16
#define NCLS 4
#define PCH 64     // pre: positions per block (= 1 wave)
#define HALO 15
#define PROWS (PCH + HALO)   // 79
#define SNC 16     // scan chunks per block
#define SCS 64     // scan chunk length

__device__ __forceinline__ float softplus_f(float x) {
    return fmaxf(x, 0.f) + log1pf(expf(-fabsf(x)));
}
__device__ __forceinline__ float silu_f(float x) {
    return x / (1.f + __expf(-x));
}

// ---- pre: thread = position; channels in registers; weights via uniform loads ----
// MODE0: u = rmsnorm(x). MODE1: u = rmsnorm(ygT^T@opw + x).
// Then in_proj -> (raw -> LDS halo), silu(z)->zT; conv+silu -> xs[48] regs -> xT;
// x_proj -> B (Bi), C (Ci + CT), dlt -> delta -> dT.
template<int MODE>
__global__ __launch_bounds__(64) void pre_kernel(
    const float* __restrict__ xin,     // (B,L,6) input / residual
    const float* __restrict__ ygT_in,  // MODE1: (B,48,L)
    const float* __restrict__ opw,     // MODE1: (48,6)
    const float* __restrict__ ipw,     // (6,96)
    const float* __restrict__ nw,      // (6)
    const float* __restrict__ cw,      // (48,16)
    const float* __restrict__ cb,      // (48)
    const float* __restrict__ xpw,     // (48,65)
    const float* __restrict__ dtw,     // (48)
    const float* __restrict__ dtb,     // (48)
    float* __restrict__ xT,            // (B,48,L)
    float* __restrict__ zT,            // (B,48,L) silu-applied
    float* __restrict__ dT,            // (B,48,L)
    float* __restrict__ Bi,            // (B,L,32)
    float* __restrict__ Ci,            // (B,L,32)
    float* __restrict__ CT)            // (B,32,L)
{
    __shared__ float s_raw[PROWS*49];

    const int tid = threadIdx.x;
    const int b  = blockIdx.x >> 4;
    const int l0 = (blockIdx.x & 15) * PCH;

    // ---- rows: rmsnorm (+proj0/residual) + in_proj ----
    for (int r = tid; r < PROWS; r += 64) {
        const int l = l0 - HALO + r;
        float u[DM] = {0,0,0,0,0,0};
        if (l >= 0) {
            const float* xr = xin + ((size_t)b*LL + l)*DM;
            #pragma unroll
            for (int d = 0; d < DM; ++d) u[d] = xr[d];
            if (MODE == 1) {
                for (int e = 0; e < 48; ++e) {
                    float v = ygT_in[((size_t)b*48 + e)*LL + l];
                    #pragma unroll
                    for (int d = 0; d < DM; ++d) u[d] = fmaf(v, opw[e*DM+d], u[d]);
                }
            }
            float ss = 0.f;
            #pragma unroll
            for (int d = 0; d < DM; ++d) ss += u[d]*u[d];
            float sc = rsqrtf(ss * (1.f/DM) + 1e-5f);
            #pragma unroll
            for (int d = 0; d < DM; ++d) u[d] *= sc * nw[d];
        }
        for (int j = 0; j < 48; ++j) {
            float acc = 0.f;
            #pragma unroll
            for (int d = 0; d < DM; ++d) acc = fmaf(u[d], ipw[d*96+j], acc);
            s_raw[r*49+j] = acc;
        }
        if (l >= l0) {
            for (int j = 48; j < 96; ++j) {
                float acc = 0.f;
                #pragma unroll
                for (int d = 0; d < DM; ++d) acc = fmaf(u[d], ipw[d*96+j], acc);
                zT[((size_t)b*48 + (j-48))*LL + l] = silu_f(acc);
            }
        }
    }
    __syncthreads();

    // ---- conv + silu: thread p owns position l0+p, xs in registers ----
    const int p = tid;
    const int l = l0 + p;
    float xs[48];
    for (int c = 0; c < 48; ++c) {
        float acc = cb[c];
        #pragma unroll
        for (int k = 0; k < DCONVK; ++k)
            acc = fmaf(s_raw[(p+k)*49 + c], cw[c*DCONVK + k], acc);
        float v = silu_f(acc);
        xs[c] = v;
        xT[((size_t)b*48 + c)*LL + l] = v;
    }

    // ---- x_proj: B pass ----
    {
        float acc[32];
        #pragma unroll
        for (int n = 0; n < 32; ++n) acc[n] = 0.f;
        for (int e = 0; e < 48; ++e) {
            const float xv = xs[e];
            const float* w = xpw + e*65 + 1;
            #pragma unroll
            for (int n = 0; n < 32; ++n) acc[n] = fmaf(xv, w[n], acc[n]);
        }
        float4* bo = (float4*)(Bi + ((size_t)b*LL + l)*32);
        #pragma unroll
        for (int k = 0; k < 8; ++k)
            bo[k] = make_float4(acc[4*k], acc[4*k+1], acc[4*k+2], acc[4*k+3]);
    }
    // ---- x_proj: C pass (both layouts) ----
    {
        float acc[32];
        #pragma unroll
        for (int n = 0; n < 32; ++n) acc[n] = 0.f;
        for (int e = 0; e < 48; ++e) {
            const float xv = xs[e];
            const float* w = xpw + e*65 + 33;
            #pragma unroll
            for (int n = 0; n < 32; ++n) acc[n] = fmaf(xv, w[n], acc[n]);
        }
        float4* co = (float4*)(Ci + ((size_t)b*LL + l)*32);
        #pragma unroll
        for (int k = 0; k < 8; ++k)
            co[k] = make_float4(acc[4*k], acc[4*k+1], acc[4*k+2], acc[4*k+3]);
        #pragma unroll
        for (int n = 0; n < 32; ++n)
            CT[((size_t)b*32 + n)*LL + l] = acc[n];
    }
    // ---- dlt + delta ----
    {
        float dlt = 0.f;
        for (int e = 0; e < 48; ++e) dlt = fmaf(xs[e], xpw[e*65], dlt);
        for (int e = 0; e < 48; ++e) {
            float xv = fmaf(dlt, dtw[e], dtb[e]);
            dT[((size_t)b*48 + e)*LL + l] = softplus_f(xv);
        }
    }
}

// ---- fused selective scan (R7 structure; phase C reads transposed CT) ----
// Block = (b,e): 512 threads = 16 half-wave units = 16 chunks of 64.
__global__ __launch_bounds__(512, 6) void scan_fused(
    const float* __restrict__ dT,
    const float* __restrict__ xT,
    const float* __restrict__ zT,     // silu(z)
    const float* __restrict__ Bi,
    const float* __restrict__ Ci,
    const float* __restrict__ CT,
    const float* __restrict__ A_log,  // (48,32)
    const float* __restrict__ Dw,     // (48)
    float* __restrict__ ygT)          // (B,48,L)
{
    __shared__ float2 sPH[SNC][32];    // (P_chunk, h_end)
    __shared__ float2 sACa[SNC][32];   // (Ac, carry)
    __shared__ float  sYL[SNC][SCS];   // local y (incl. D*x)
    __shared__ float  sS [SNC][SCS];   // delta prefix within chunk

    const int tid = threadIdx.x;
    const int lane = tid & 63;
    const int ch = lane >> 5, n = lane & 31;
    const int c = (tid >> 6)*2 + ch;
    const int b = blockIdx.x / 48;
    const int e = blockIdx.x % 48;

    const float Ac = -__expf(A_log[e*NST + n]);
    const float Dc = Dw[e];

    const size_t eb = ((size_t)b*48 + e)*LL + c*SCS;
    const float4* dp = (const float4*)(dT + eb);
    const float4* xp = (const float4*)(xT + eb);
    const float*  bp = Bi + ((size_t)b*LL + c*SCS)*32 + n;
    const float*  cp = Ci + ((size_t)b*LL + c*SCS)*32 + n;

    float h = 0.f, S = 0.f;

    // phase A
    #pragma unroll
    for (int q = 0; q < SCS/4; ++q) {
        float4 d4 = dp[q], x4 = xp[q];
        float b0 = bp[(4*q+0)*32], b1 = bp[(4*q+1)*32];
        float b2 = bp[(4*q+2)*32], b3 = bp[(4*q+3)*32];
        float c0 = cp[(4*q+0)*32], c1 = cp[(4*q+1)*32];
        float c2 = cp[(4*q+2)*32], c3 = cp[(4*q+3)*32];
        float p0, p1, p2, p3;
        h = fmaf(__expf(d4.x*Ac), h, d4.x*x4.x*b0); p0 = h*c0;
        h = fmaf(__expf(d4.y*Ac), h, d4.y*x4.y*b1); p1 = h*c1;
        h = fmaf(__expf(d4.z*Ac), h, d4.z*x4.z*b2); p2 = h*c2;
        h = fmaf(__expf(d4.w*Ac), h, d4.w*x4.w*b3); p3 = h*c3;
        float s0 = S + d4.x, s1 = s0 + d4.y, s2 = s1 + d4.z, s3 = s2 + d4.w;
        S = s3;
        if (n == 0) *(float4*)&sS[c][4*q] = make_float4(s0, s1, s2, s3);
        float q0 = p0 + __shfl_xor(p0, 16);
        float q1 = p1 + __shfl_xor(p1, 16);
        float q2 = p2 + __shfl_xor(p2, 16);
        float q3 = p3 + __shfl_xor(p3, 16);
        float m01 = (n & 16) ? q1 : q0;
        float m23 = (n & 16) ? q3 : q2;
        m01 += __shfl_xor(m01, 8);
        m23 += __shfl_xor(m23, 8);
        float mm = (n & 8) ? m23 : m01;
        mm += __shfl_xor(mm, 4);
        mm += __shfl_xor(mm, 2);
        mm += __shfl_xor(mm, 1);
        if ((n & 7) == 0) {
            int vidx = ((n >> 4) & 1) | (((n >> 3) & 1) << 1);
            float xv = (vidx & 2) ? ((vidx & 1) ? x4.w : x4.z)
                                  : ((vidx & 1) ? x4.y : x4.x);
            sYL[c][4*q + vidx] = fmaf(Dc, xv, mm);
        }
    }
    sPH[c][n] = make_float2(__expf(Ac*S), h);
    __syncthreads();

    // phase B: carry scan over 16 chunks (one 32-lane unit)
    if (tid < 32) {
        float2 v[SNC];
        #pragma unroll
        for (int k = 0; k < SNC; ++k) v[k] = sPH[k][tid];
        float acc = 0.f;
        #pragma unroll
        for (int k = 0; k < SNC; ++k) {
            sACa[k][tid] = make_float2(Ac, acc);
            acc = fmaf(v[k].x, acc, v[k].y);
        }
    }
    __syncthreads();

    // phase C: thread = (chunk, t), 2 rounds; coalesced CT loads
    #pragma unroll
    for (int r = 0; r < 2; ++r) {
        const int c2 = (tid >> 6) + 8*r;
        const int t = lane;
        const float St = sS[c2][t];
        const float yl = sYL[c2][t];
        const float* ctp = CT + (size_t)b*32*LL + c2*SCS + t;
        float corr = 0.f;
        #pragma unroll
        for (int n2 = 0; n2 < 32; ++n2) {
            float2 w = sACa[c2][n2];
            corr = fmaf(ctp[(size_t)n2*LL] * __expf(w.x*St), w.y, corr);
        }
        const size_t o = ((size_t)b*48 + e)*LL + c2*SCS + t;
        ygT[o] = (yl + corr) * zT[o];
    }
}

// ---- head ----
__global__ __launch_bounds__(1024) void head_kernel(
    const float* __restrict__ ygT,
    const float* __restrict__ fcw, const float* __restrict__ fcb,
    const float* __restrict__ clw, const float* __restrict__ clb,
    const float* __restrict__ rgw, const float* __restrict__ rgb,
    float* __restrict__ out)
{
    __shared__ float s_h[BB*48];
    __shared__ float s_f[BB*48];
    const int tid = threadIdx.x;
    const int b = tid >> 6, j = tid & 63;
    if (j < 48) s_h[b*48+j] = ygT[((size_t)b*48 + j)*LL + (LL-1)];
    __syncthreads();
    if (j < 48) {
        float acc = fcb[j];
        for (int k = 0; k < 48; ++k) acc += s_h[b*48+k]*fcw[k*48+j];
        s_f[b*48+j] = fmaxf(acc, 0.f);
    }
    __syncthreads();
    if (j < NCLS) {
        float acc = clb[j];
        for (int k = 0; k < 48; ++k) acc += s_f[b*48+k]*clw[k*NCLS+j];
        out[b*NCLS + j] = acc;
    }
    if (j == NCLS) {
        float acc = rgb[0];
        for (int k = 0; k < 48; ++k) acc += s_f[b*48+k]*rgw[k];
        out[BB*NCLS + b] = acc;
    }
}

extern "C" void kernel_launch(void* const* d_in, const int* in_sizes, int n_in,
                              void* d_out, int out_size, void* d_ws, size_t ws_size,
                              hipStream_t stream)
{
    const float* x     = (const float*)d_in[0];
    const float* ipw   = (const float*)d_in[1];
    const float* cw    = (const float*)d_in[2];
    const float* cb    = (const float*)d_in[3];
    const float* xpw   = (const float*)d_in[4];
    const float* dtw   = (const float*)d_in[5];
    const float* dtb   = (const float*)d_in[6];
    const float* A_log = (const float*)d_in[7];
    const float* Dw    = (const float*)d_in[8];
    const float* nw    = (const float*)d_in[9];
    const float* opw   = (const float*)d_in[10];
    const float* fcw   = (const float*)d_in[11];
    const float* fcb   = (const float*)d_in[12];
    const float* clw   = (const float*)d_in[13];
    const float* clb   = (const float*)d_in[14];
    const float* rgw   = (const float*)d_in[15];
    const float* rgb   = (const float*)d_in[16];
    float* out = (float*)d_out;

    float* ws = (float*)d_ws;
    const size_t BL = (size_t)BB*LL;
    float* xT  = ws;
    float* zT  = xT  + BL*48;
    float* dT  = zT  + BL*48;
    float* Bi  = dT  + BL*48;
    float* Ci  = Bi  + BL*32;
    float* CT  = Ci  + BL*32;
    float* ygT = CT  + BL*32;

    const dim3 preGrid(BB*16), preBlk(64);
    const dim3 scanGrid(BB*48), scanBlk(512);

    // ---- layer 0 ----
    pre_kernel<0><<<preGrid, preBlk, 0, stream>>>(
        x, nullptr, nullptr, ipw, nw, cw, cb, xpw, dtw, dtb,
        xT, zT, dT, Bi, Ci, CT);
    scan_fused<<<scanGrid, scanBlk, 0, stream>>>(
        dT, xT, zT, Bi, Ci, CT, A_log, Dw, ygT);

    // ---- layer 1 ----
    pre_kernel<1><<<preGrid, preBlk, 0, stream>>>(
        x, ygT, opw, ipw + 576, nw + 6, cw + 768, cb + 48,
        xpw + 3120, dtw + 48, dtb + 48,
        xT, zT, dT, Bi, Ci, CT);
    scan_fused<<<scanGrid, scanBlk, 0, stream>>>(
        dT, xT, zT, Bi, Ci, CT, A_log + 1536, Dw + 48, ygT);

    head_kernel<<<dim3(1), dim3(1024), 0, stream>>>(
        ygT, fcw, fcb, clw, clb, rgw, rgb, out);
}

// Round 11
// 179.677 us; speedup vs baseline: 1.7840x; 1.7199x over previous
//
#include <hip/hip_runtime.h>
#include <math.h>

#define BB 16
#define LL 1024
#define DM 6
#define NST 32
#define DCONVK 16
#define NCLS 4
#define CH 16    // positions per pre-kernel block
#define HALO 15
#define SNC 32   // scan chunks per block
#define SCS 32   // scan chunk length (SNC*SCS = LL)

__device__ __forceinline__ float softplus_f(float x) {
    return fmaxf(x, 0.f) + log1pf(expf(-fabsf(x)));
}
__device__ __forceinline__ float silu_f(float x) {
    return x / (1.f + __expf(-x));
}

// Fused: [MODE0: rmsnorm(x)] / [MODE1: ygT@opw + x residual -> rmsnorm]
//        -> in_proj -> split -> causal dwconv+silu -> x_proj -> softplus(delta)
// Outputs: xT/dT (B,48,L); zT = silu(z) (B,48,L); Bi/Ci (B,L,32); CT (B,32,L).
template<int MODE>
__global__ __launch_bounds__(256, 4) void pre_kernel(
    const float* __restrict__ hin,     // x (B,L,6): MODE0 input / MODE1 residual
    const float* __restrict__ ygT_in,  // MODE1: (B,48,L)
    const float* __restrict__ opw,     // MODE1: (48,6)
    const float* __restrict__ ipw,     // (6,96)
    const float* __restrict__ nw,      // (6)
    const float* __restrict__ cw,      // (48,16)
    const float* __restrict__ cb,      // (48)
    const float* __restrict__ xpw,     // (48,65)
    const float* __restrict__ dtw,     // (48)
    const float* __restrict__ dtb,     // (48)
    float* __restrict__ xT,            // (B,48,L)
    float* __restrict__ zT,            // (B,48,L)  silu-applied
    float* __restrict__ dT,            // (B,48,L)
    float* __restrict__ Bi,            // (B,L,32)
    float* __restrict__ Ci,            // (B,L,32)
    float* __restrict__ CT)            // (B,32,L)
{
    __shared__ float s_ipw[6*96];
    __shared__ float s_nw[6];
    __shared__ float s_cw[48*DCONVK];
    __shared__ float s_cb[48];
    __shared__ float s_xpw[48*65];
    __shared__ float s_dtw[48];
    __shared__ float s_dtb[48];
    __shared__ float s_opw[48*6];
    __shared__ float s_pp[(CH+HALO)*4*6];
    __shared__ float s_u[(CH+HALO)*7];
    __shared__ float s_raw[(CH+HALO)*49];
    __shared__ float s_xsT[48*CH];        // [c][p] channel-major
    __shared__ float s_bc[64*(CH+1)];     // [col][p] for B/C transpose-out
    __shared__ float s_dlt[CH];

    const int tid = threadIdx.x;
    const int b  = blockIdx.x >> 6;
    const int l0 = (blockIdx.x & 63) * CH;
    const int ROWS = CH + HALO;           // 31

    for (int i = tid; i < 6*96; i += 256) s_ipw[i] = ipw[i];
    if (tid < 6) s_nw[tid] = nw[tid];
    for (int i = tid; i < 48*DCONVK; i += 256) s_cw[i] = cw[i];
    if (tid < 48) s_cb[tid] = cb[tid];
    for (int i = tid; i < 48*65; i += 256) s_xpw[i] = xpw[i];
    if (tid < 48) { s_dtw[tid] = dtw[tid]; s_dtb[tid] = dtb[tid]; }
    if (MODE == 1) for (int i = tid; i < 48*6; i += 256) s_opw[i] = opw[i];
    __syncthreads();

    // ---- phase 0: produce s_u (normalized rows l0-15 .. l0+CH-1) ----
    if (MODE == 0) {
        if (tid < ROWS) {
            int l = l0 - HALO + tid;
            float u[DM];
            if (l >= 0) {
                float ss = 0.f;
                const float* hp = hin + ((size_t)b*LL + l)*DM;
                #pragma unroll
                for (int d = 0; d < DM; ++d) { u[d] = hp[d]; ss += u[d]*u[d]; }
                float sc = rsqrtf(ss * (1.f/DM) + 1e-5f);
                #pragma unroll
                for (int d = 0; d < DM; ++d) u[d] *= sc * s_nw[d];
            } else {
                #pragma unroll
                for (int d = 0; d < DM; ++d) u[d] = 0.f;
            }
            #pragma unroll
            for (int d = 0; d < DM; ++d) s_u[tid*7+d] = u[d];
        }
        __syncthreads();
    } else {
        // proj0 fused: ygT^T @ opw (4 e-groups), + residual, rmsnorm
        const int g = tid >> 6, t = tid & 63;
        if (t < ROWS) {
            int l = l0 - HALO + t;
            float pacc[DM] = {0,0,0,0,0,0};
            if (l >= 0) {
                for (int e = g*12; e < g*12 + 12; ++e) {
                    float v = ygT_in[((size_t)b*48 + e)*LL + l];
                    #pragma unroll
                    for (int d = 0; d < DM; ++d) pacc[d] += v * s_opw[e*DM+d];
                }
            }
            #pragma unroll
            for (int d = 0; d < DM; ++d) s_pp[(t*4+g)*DM+d] = pacc[d];
        }
        __syncthreads();
        if (tid < ROWS) {
            int l = l0 - HALO + tid;
            float u[DM];
            if (l >= 0) {
                const float* xr = hin + ((size_t)b*LL + l)*DM;
                float ss = 0.f;
                #pragma unroll
                for (int d = 0; d < DM; ++d) {
                    float hv = s_pp[(tid*4+0)*DM+d] + s_pp[(tid*4+1)*DM+d]
                             + s_pp[(tid*4+2)*DM+d] + s_pp[(tid*4+3)*DM+d] + xr[d];
                    u[d] = hv; ss += hv*hv;
                }
                float sc = rsqrtf(ss * (1.f/DM) + 1e-5f);
                #pragma unroll
                for (int d = 0; d < DM; ++d) u[d] *= sc * s_nw[d];
            } else {
                #pragma unroll
                for (int d = 0; d < DM; ++d) u[d] = 0.f;
            }
            #pragma unroll
            for (int d = 0; d < DM; ++d) s_u[tid*7+d] = u[d];
        }
        __syncthreads();
    }

    // ---- phase 1: in_proj (96 cols x ROWS rows); z gets silu applied ----
    for (int i = tid; i < 96*ROWS; i += 256) {
        int j = i / ROWS, t = i - j*ROWS;
        float acc = 0.f;
        #pragma unroll
        for (int d = 0; d < DM; ++d) acc += s_u[t*7+d]*s_ipw[d*96+j];
        if (j < 48) s_raw[t*49+j] = acc;
        else if (t >= HALO)
            zT[((size_t)b*48 + (j-48))*LL + (l0 - HALO + t)] = silu_f(acc);
    }
    __syncthreads();

    // ---- phase 2: depthwise causal conv (K=16) + silu ----
    for (int o = tid; o < 48*CH; o += 256) {
        int c = o >> 4, p = o & 15;
        float acc = s_cb[c];
        #pragma unroll
        for (int k = 0; k < DCONVK; ++k)
            acc += s_raw[(p+k)*49 + c] * s_cw[c*DCONVK + k];
        float v = silu_f(acc);
        s_xsT[c*CH + p] = v;
        xT[((size_t)b*48 + c)*LL + l0 + p] = v;
    }
    __syncthreads();

    // ---- phase 3: x_proj. thread = (col j:64, pos-group g:4) ----
    {
        const int j = tid >> 2, g = tid & 3;
        float a0=0,a1=0,a2=0,a3=0;
        for (int e = 0; e < 48; ++e) {
            float4 xv = *(const float4*)&s_xsT[e*CH + 4*g];
            float w = s_xpw[e*65 + 1 + j];
            a0 = fmaf(xv.x, w, a0); a1 = fmaf(xv.y, w, a1);
            a2 = fmaf(xv.z, w, a2); a3 = fmaf(xv.w, w, a3);
        }
        s_bc[j*(CH+1) + 4*g+0] = a0; s_bc[j*(CH+1) + 4*g+1] = a1;
        s_bc[j*(CH+1) + 4*g+2] = a2; s_bc[j*(CH+1) + 4*g+3] = a3;
    }
    if (tid < CH) {
        float acc = 0.f;
        for (int e = 0; e < 48; ++e) acc += s_xsT[e*CH + tid]*s_xpw[e*65];
        s_dlt[tid] = acc;
    }
    __syncthreads();

    // ---- phase 3b: write B/C interleaved + C transposed ----
    for (int o = tid; o < 2*CH*32; o += 256) {
        int which = o >> 9;             // 0:B 1:C
        int l = (o >> 5) & (CH-1), n = o & 31;
        float v = s_bc[(which*32 + n)*(CH+1) + l];
        float* dst = which ? Ci : Bi;
        dst[((size_t)b*LL + l0 + l)*32 + n] = v;
    }
    for (int o = tid; o < 32*CH; o += 256) {
        int n = o >> 4, l = o & (CH-1);
        CT[((size_t)b*32 + n)*LL + l0 + l] = s_bc[(32+n)*(CH+1) + l];
    }

    // ---- phase 4: delta = softplus(dlt*dt_w + dt_b), transposed write ----
    for (int o = tid; o < 48*CH; o += 256) {
        int e = o >> 4, p = o & 15;
        float xv = s_dlt[p]*s_dtw[e] + s_dtb[e];
        dT[((size_t)b*48 + e)*LL + l0 + p] = softplus_f(xv);
    }
}

// ---- fused selective scan ----
// Block = (b,e): 1024 threads = 32 half-wave units = 32 chunks of 32 steps.
// Phase A (lane=n): local h-scan; local-y via 9-shfl scattered butterfly;
//   delta prefix S into LDS; (P, h_end) per chunk.
// Phase B: one 32-lane unit scans 32 chunk carries (batched preload).
// Phase C (thread=(chunk,t)): corr = sum_n CT[n]*exp(Ac[n]*S_t)*carry[n],
//   coalesced CT reads; y = (y_local + corr) * silu_z.
__global__ __launch_bounds__(1024, 8) void scan_fused(
    const float* __restrict__ dT,
    const float* __restrict__ xT,
    const float* __restrict__ zT,     // silu(z)
    const float* __restrict__ Bi,
    const float* __restrict__ Ci,
    const float* __restrict__ CT,
    const float* __restrict__ A_log,  // (48,32)
    const float* __restrict__ Dw,     // (48)
    float* __restrict__ ygT)          // (B,48,L)
{
    __shared__ float2 sPH[SNC][32];    // (P_chunk, h_end)
    __shared__ float2 sACa[SNC][32];   // (Ac, carry)
    __shared__ float  sYL[SNC][SCS];   // local y (incl. D*x)
    __shared__ float  sS [SNC][SCS];   // delta prefix within chunk

    const int tid = threadIdx.x;
    const int lane = tid & 63;
    const int ch = lane >> 5, n = lane & 31;
    const int c = ((tid >> 6) << 1) | ch;   // chunk 0..31
    const int b = blockIdx.x / 48;
    const int e = blockIdx.x % 48;

    const float Ac = -__expf(A_log[e*NST + n]);
    const float Dc = Dw[e];

    const size_t eb = ((size_t)b*48 + e)*LL + c*SCS;
    const float4* dp = (const float4*)(dT + eb);
    const float4* xp = (const float4*)(xT + eb);
    const float*  bp = Bi + ((size_t)b*LL + c*SCS)*32 + n;
    const float*  cp = Ci + ((size_t)b*LL + c*SCS)*32 + n;

    float h = 0.f, S = 0.f;

    // ---- phase A ----
    #pragma unroll
    for (int q = 0; q < SCS/4; ++q) {
        float4 d4 = dp[q], x4 = xp[q];
        float b0 = bp[(4*q+0)*32], b1 = bp[(4*q+1)*32];
        float b2 = bp[(4*q+2)*32], b3 = bp[(4*q+3)*32];
        float c0 = cp[(4*q+0)*32], c1 = cp[(4*q+1)*32];
        float c2 = cp[(4*q+2)*32], c3 = cp[(4*q+3)*32];
        float p0, p1, p2, p3;
        h = fmaf(__expf(d4.x*Ac), h, d4.x*x4.x*b0); p0 = h*c0;
        h = fmaf(__expf(d4.y*Ac), h, d4.y*x4.y*b1); p1 = h*c1;
        h = fmaf(__expf(d4.z*Ac), h, d4.z*x4.z*b2); p2 = h*c2;
        h = fmaf(__expf(d4.w*Ac), h, d4.w*x4.w*b3); p3 = h*c3;
        float s0 = S + d4.x, s1 = s0 + d4.y, s2 = s1 + d4.z, s3 = s2 + d4.w;
        S = s3;
        if (n == 0) *(float4*)&sS[c][4*q] = make_float4(s0, s1, s2, s3);
        float q0 = p0 + __shfl_xor(p0, 16);
        float q1 = p1 + __shfl_xor(p1, 16);
        float q2 = p2 + __shfl_xor(p2, 16);
        float q3 = p3 + __shfl_xor(p3, 16);
        float m01 = (n & 16) ? q1 : q0;
        float m23 = (n & 16) ? q3 : q2;
        m01 += __shfl_xor(m01, 8);
        m23 += __shfl_xor(m23, 8);
        float mm = (n & 8) ? m23 : m01;
        mm += __shfl_xor(mm, 4);
        mm += __shfl_xor(mm, 2);
        mm += __shfl_xor(mm, 1);
        if ((n & 7) == 0) {
            int vidx = ((n >> 4) & 1) | (((n >> 3) & 1) << 1);
            float xv = (vidx & 2) ? ((vidx & 1) ? x4.w : x4.z)
                                  : ((vidx & 1) ? x4.y : x4.x);
            sYL[c][4*q + vidx] = fmaf(Dc, xv, mm);
        }
    }
    sPH[c][n] = make_float2(__expf(Ac*S), h);
    __syncthreads();

    // ---- phase B: carry scan over 32 chunks (one 32-lane unit, batched) ----
    if (tid < 32) {
        float acc = 0.f;
        #pragma unroll
        for (int batch = 0; batch < 4; ++batch) {
            float2 v[8];
            #pragma unroll
            for (int k = 0; k < 8; ++k) v[k] = sPH[batch*8+k][tid];
            #pragma unroll
            for (int k = 0; k < 8; ++k) {
                sACa[batch*8+k][tid] = make_float2(Ac, acc);
                acc = fmaf(v[k].x, acc, v[k].y);
            }
        }
    }
    __syncthreads();

    // ---- phase C: thread = (chunk, t); coalesced CT reads ----
    {
        const int c2 = tid >> 5;
        const int t = tid & 31;
        const float St = sS[c2][t];
        const float yl = sYL[c2][t];
        const float* ctp = CT + (size_t)b*32*LL + c2*SCS + t;
        float corr = 0.f;
        #pragma unroll
        for (int n2 = 0; n2 < 32; ++n2) {
            float2 w = sACa[c2][n2];
            corr = fmaf(ctp[(size_t)n2*LL] * __expf(w.x*St), w.y, corr);
        }
        const size_t o = ((size_t)b*48 + e)*LL + c2*SCS + t;
        ygT[o] = (yl + corr) * zT[o];
    }
}

// ---- head ----
__global__ __launch_bounds__(1024) void head_kernel(
    const float* __restrict__ ygT,
    const float* __restrict__ fcw, const float* __restrict__ fcb,
    const float* __restrict__ clw, const float* __restrict__ clb,
    const float* __restrict__ rgw, const float* __restrict__ rgb,
    float* __restrict__ out)
{
    __shared__ float s_h[BB*48];
    __shared__ float s_f[BB*48];
    const int tid = threadIdx.x;
    const int b = tid >> 6, j = tid & 63;
    if (j < 48) s_h[b*48+j] = ygT[((size_t)b*48 + j)*LL + (LL-1)];
    __syncthreads();
    if (j < 48) {
        float acc = fcb[j];
        for (int k = 0; k < 48; ++k) acc += s_h[b*48+k]*fcw[k*48+j];
        s_f[b*48+j] = fmaxf(acc, 0.f);
    }
    __syncthreads();
    if (j < NCLS) {
        float acc = clb[j];
        for (int k = 0; k < 48; ++k) acc += s_f[b*48+k]*clw[k*NCLS+j];
        out[b*NCLS + j] = acc;
    }
    if (j == NCLS) {
        float acc = rgb[0];
        for (int k = 0; k < 48; ++k) acc += s_f[b*48+k]*rgw[k];
        out[BB*NCLS + b] = acc;
    }
}

extern "C" void kernel_launch(void* const* d_in, const int* in_sizes, int n_in,
                              void* d_out, int out_size, void* d_ws, size_t ws_size,
                              hipStream_t stream)
{
    const float* x     = (const float*)d_in[0];
    const float* ipw   = (const float*)d_in[1];
    const float* cw    = (const float*)d_in[2];
    const float* cb    = (const float*)d_in[3];
    const float* xpw   = (const float*)d_in[4];
    const float* dtw   = (const float*)d_in[5];
    const float* dtb   = (const float*)d_in[6];
    const float* A_log = (const float*)d_in[7];
    const float* Dw    = (const float*)d_in[8];
    const float* nw    = (const float*)d_in[9];
    const float* opw   = (const float*)d_in[10];
    const float* fcw   = (const float*)d_in[11];
    const float* fcb   = (const float*)d_in[12];
    const float* clw   = (const float*)d_in[13];
    const float* clb   = (const float*)d_in[14];
    const float* rgw   = (const float*)d_in[15];
    const float* rgb   = (const float*)d_in[16];
    float* out = (float*)d_out;

    float* ws = (float*)d_ws;
    const size_t BL = (size_t)BB*LL;
    float* xT  = ws;
    float* zT  = xT  + BL*48;
    float* dT  = zT  + BL*48;
    float* Bi  = dT  + BL*48;
    float* Ci  = Bi  + BL*32;
    float* CT  = Ci  + BL*32;
    float* ygT = CT  + BL*32;

    const dim3 preGrid(BB*64), preBlk(256);
    const dim3 scanGrid(BB*48), scanBlk(1024);

    // ---- layer 0 ----
    pre_kernel<0><<<preGrid, preBlk, 0, stream>>>(
        x, nullptr, nullptr, ipw, nw, cw, cb, xpw, dtw, dtb,
        xT, zT, dT, Bi, Ci, CT);
    scan_fused<<<scanGrid, scanBlk, 0, stream>>>(
        dT, xT, zT, Bi, Ci, CT, A_log, Dw, ygT);

    // ---- layer 1 ----
    pre_kernel<1><<<preGrid, preBlk, 0, stream>>>(
        x, ygT, opw, ipw + 576, nw + 6, cw + 768, cb + 48,
        xpw + 3120, dtw + 48, dtb + 48,
        xT, zT, dT, Bi, Ci, CT);
    scan_fused<<<scanGrid, scanBlk, 0, stream>>>(
        dT, xT, zT, Bi, Ci, CT, A_log + 1536, Dw + 48, ygT);

    head_kernel<<<dim3(1), dim3(1024), 0, stream>>>(
        ygT, fcw, fcb, clw, clb, rgw, rgb, out);
}

// Round 12
// 177.475 us; speedup vs baseline: 1.8061x; 1.0124x over previous
//
#include <hip/hip_runtime.h>
#include <math.h>

#define BB 16
#define LL 1024
#define DM 6
#define NST 32
#define DCONVK 16
#define NCLS 4
#define CH 16    // positions per pre-kernel block
#define HALO 15
#define SNC 32   // scan chunks per block
#define SCS 32   // scan chunk length (SNC*SCS = LL)

__device__ __forceinline__ float softplus_f(float x) {
    return fmaxf(x, 0.f) + log1pf(expf(-fabsf(x)));
}
__device__ __forceinline__ float silu_f(float x) {
    return x / (1.f + __expf(-x));
}

// Fused: [MODE0: rmsnorm(x)] / [MODE1: ygT@opw + x residual -> rmsnorm]
//        -> in_proj -> split -> causal dwconv+silu -> x_proj -> softplus(delta)
// Outputs: xT/dT (B,48,L); zT = silu(z) (B,48,L);
//          Bi4/Ci4 packed (B,L/4,32,4); CT (B,32,L).
template<int MODE>
__global__ __launch_bounds__(256, 4) void pre_kernel(
    const float* __restrict__ hin,     // x (B,L,6): MODE0 input / MODE1 residual
    const float* __restrict__ ygT_in,  // MODE1: (B,48,L)
    const float* __restrict__ opw,     // MODE1: (48,6)
    const float* __restrict__ ipw,     // (6,96)
    const float* __restrict__ nw,      // (6)
    const float* __restrict__ cw,      // (48,16)
    const float* __restrict__ cb,      // (48)
    const float* __restrict__ xpw,     // (48,65)
    const float* __restrict__ dtw,     // (48)
    const float* __restrict__ dtb,     // (48)
    float* __restrict__ xT,            // (B,48,L)
    float* __restrict__ zT,            // (B,48,L)  silu-applied
    float* __restrict__ dT,            // (B,48,L)
    float* __restrict__ Bi4,           // (B,L/4,32,4)
    float* __restrict__ Ci4,           // (B,L/4,32,4)
    float* __restrict__ CT)            // (B,32,L)
{
    __shared__ float s_ipw[6*96];
    __shared__ float s_nw[6];
    __shared__ float s_cw[48*DCONVK];
    __shared__ float s_cb[48];
    __shared__ float s_xpw[48*65];
    __shared__ float s_dtw[48];
    __shared__ float s_dtb[48];
    __shared__ float s_opw[48*6];
    __shared__ float s_pp[(CH+HALO)*4*6];
    __shared__ float s_u[(CH+HALO)*7];
    __shared__ float s_raw[(CH+HALO)*49];
    __shared__ float s_xsT[48*CH];        // [c][p] channel-major
    __shared__ float s_bc[64*(CH+1)];     // [col][p] for B/C transpose-out
    __shared__ float s_dlt[CH];

    const int tid = threadIdx.x;
    const int b  = blockIdx.x >> 6;
    const int l0 = (blockIdx.x & 63) * CH;
    const int ROWS = CH + HALO;           // 31

    for (int i = tid; i < 6*96; i += 256) s_ipw[i] = ipw[i];
    if (tid < 6) s_nw[tid] = nw[tid];
    for (int i = tid; i < 48*DCONVK; i += 256) s_cw[i] = cw[i];
    if (tid < 48) s_cb[tid] = cb[tid];
    for (int i = tid; i < 48*65; i += 256) s_xpw[i] = xpw[i];
    if (tid < 48) { s_dtw[tid] = dtw[tid]; s_dtb[tid] = dtb[tid]; }
    if (MODE == 1) for (int i = tid; i < 48*6; i += 256) s_opw[i] = opw[i];
    __syncthreads();

    // ---- phase 0: produce s_u (normalized rows l0-15 .. l0+CH-1) ----
    if (MODE == 0) {
        if (tid < ROWS) {
            int l = l0 - HALO + tid;
            float u[DM];
            if (l >= 0) {
                float ss = 0.f;
                const float* hp = hin + ((size_t)b*LL + l)*DM;
                #pragma unroll
                for (int d = 0; d < DM; ++d) { u[d] = hp[d]; ss += u[d]*u[d]; }
                float sc = rsqrtf(ss * (1.f/DM) + 1e-5f);
                #pragma unroll
                for (int d = 0; d < DM; ++d) u[d] *= sc * s_nw[d];
            } else {
                #pragma unroll
                for (int d = 0; d < DM; ++d) u[d] = 0.f;
            }
            #pragma unroll
            for (int d = 0; d < DM; ++d) s_u[tid*7+d] = u[d];
        }
        __syncthreads();
    } else {
        // proj0 fused: ygT^T @ opw (4 e-groups), + residual, rmsnorm
        const int g = tid >> 6, t = tid & 63;
        if (t < ROWS) {
            int l = l0 - HALO + t;
            float pacc[DM] = {0,0,0,0,0,0};
            if (l >= 0) {
                for (int e = g*12; e < g*12 + 12; ++e) {
                    float v = ygT_in[((size_t)b*48 + e)*LL + l];
                    #pragma unroll
                    for (int d = 0; d < DM; ++d) pacc[d] += v * s_opw[e*DM+d];
                }
            }
            #pragma unroll
            for (int d = 0; d < DM; ++d) s_pp[(t*4+g)*DM+d] = pacc[d];
        }
        __syncthreads();
        if (tid < ROWS) {
            int l = l0 - HALO + tid;
            float u[DM];
            if (l >= 0) {
                const float* xr = hin + ((size_t)b*LL + l)*DM;
                float ss = 0.f;
                #pragma unroll
                for (int d = 0; d < DM; ++d) {
                    float hv = s_pp[(tid*4+0)*DM+d] + s_pp[(tid*4+1)*DM+d]
                             + s_pp[(tid*4+2)*DM+d] + s_pp[(tid*4+3)*DM+d] + xr[d];
                    u[d] = hv; ss += hv*hv;
                }
                float sc = rsqrtf(ss * (1.f/DM) + 1e-5f);
                #pragma unroll
                for (int d = 0; d < DM; ++d) u[d] *= sc * s_nw[d];
            } else {
                #pragma unroll
                for (int d = 0; d < DM; ++d) u[d] = 0.f;
            }
            #pragma unroll
            for (int d = 0; d < DM; ++d) s_u[tid*7+d] = u[d];
        }
        __syncthreads();
    }

    // ---- phase 1: in_proj (96 cols x ROWS rows); z gets silu applied ----
    for (int i = tid; i < 96*ROWS; i += 256) {
        int j = i / ROWS, t = i - j*ROWS;
        float acc = 0.f;
        #pragma unroll
        for (int d = 0; d < DM; ++d) acc += s_u[t*7+d]*s_ipw[d*96+j];
        if (j < 48) s_raw[t*49+j] = acc;
        else if (t >= HALO)
            zT[((size_t)b*48 + (j-48))*LL + (l0 - HALO + t)] = silu_f(acc);
    }
    __syncthreads();

    // ---- phase 2: depthwise causal conv (K=16) + silu ----
    for (int o = tid; o < 48*CH; o += 256) {
        int c = o >> 4, p = o & 15;
        float acc = s_cb[c];
        #pragma unroll
        for (int k = 0; k < DCONVK; ++k)
            acc += s_raw[(p+k)*49 + c] * s_cw[c*DCONVK + k];
        float v = silu_f(acc);
        s_xsT[c*CH + p] = v;
        xT[((size_t)b*48 + c)*LL + l0 + p] = v;
    }
    __syncthreads();

    // ---- phase 3: x_proj. thread = (col j:64, pos-group g:4) ----
    {
        const int j = tid >> 2, g = tid & 3;
        float a0=0,a1=0,a2=0,a3=0;
        for (int e = 0; e < 48; ++e) {
            float4 xv = *(const float4*)&s_xsT[e*CH + 4*g];
            float w = s_xpw[e*65 + 1 + j];
            a0 = fmaf(xv.x, w, a0); a1 = fmaf(xv.y, w, a1);
            a2 = fmaf(xv.z, w, a2); a3 = fmaf(xv.w, w, a3);
        }
        s_bc[j*(CH+1) + 4*g+0] = a0; s_bc[j*(CH+1) + 4*g+1] = a1;
        s_bc[j*(CH+1) + 4*g+2] = a2; s_bc[j*(CH+1) + 4*g+3] = a3;
    }
    if (tid < CH) {
        float acc = 0.f;
        for (int e = 0; e < 48; ++e) acc += s_xsT[e*CH + tid]*s_xpw[e*65];
        s_dlt[tid] = acc;
    }
    __syncthreads();

    // ---- phase 3b: write B/C packed (B,L/4,32,4) + C transposed ----
    for (int o = tid; o < 2*(CH/4)*32; o += 256) {    // 256 items exactly
        int which = o >> 7;                 // 0:B 1:C
        int lg = (o >> 5) & (CH/4 - 1), n = o & 31;
        const float* src = &s_bc[(which*32 + n)*(CH+1) + 4*lg];
        float4 v = make_float4(src[0], src[1], src[2], src[3]);
        float4* dst = (float4*)(which ? Ci4 : Bi4);
        dst[((size_t)b*(LL/4) + (l0/4 + lg))*32 + n] = v;
    }
    for (int o = tid; o < 32*CH; o += 256) {
        int n = o >> 4, l = o & (CH-1);
        CT[((size_t)b*32 + n)*LL + l0 + l] = s_bc[(32+n)*(CH+1) + l];
    }

    // ---- phase 4: delta = softplus(dlt*dt_w + dt_b), transposed write ----
    for (int o = tid; o < 48*CH; o += 256) {
        int e = o >> 4, p = o & 15;
        float xv = s_dlt[p]*s_dtw[e] + s_dtb[e];
        dT[((size_t)b*48 + e)*LL + l0 + p] = softplus_f(xv);
    }
}

// ---- fused selective scan ----
// Block = (b,e): 1024 threads = 32 half-wave units = 32 chunks of 32 steps.
// Phase A (lane=n): local h-scan; B/C via packed float4 (1 VMEM instr each
//   per 4 steps); local-y via 9-shfl scattered butterfly; S prefix to LDS.
// Phase B: one 32-lane unit scans 32 chunk carries (batched preload).
// Phase C (thread=(chunk,t)): corr = sum_n CT[n]*exp(Ac[n]*S_t)*carry[n],
//   coalesced CT reads; y = (y_local + corr) * silu_z.
__global__ __launch_bounds__(1024, 8) void scan_fused(
    const float* __restrict__ dT,
    const float* __restrict__ xT,
    const float* __restrict__ zT,     // silu(z)
    const float* __restrict__ Bi4,    // (B,L/4,32,4)
    const float* __restrict__ Ci4,    // (B,L/4,32,4)
    const float* __restrict__ CT,     // (B,32,L)
    const float* __restrict__ A_log,  // (48,32)
    const float* __restrict__ Dw,     // (48)
    float* __restrict__ ygT)          // (B,48,L)
{
    __shared__ float2 sPH[SNC][32];    // (P_chunk, h_end)
    __shared__ float2 sACa[SNC][32];   // (Ac, carry)
    __shared__ float  sYL[SNC][SCS];   // local y (incl. D*x)
    __shared__ float  sS [SNC][SCS];   // delta prefix within chunk

    const int tid = threadIdx.x;
    const int lane = tid & 63;
    const int ch = lane >> 5, n = lane & 31;
    const int c = ((tid >> 6) << 1) | ch;   // chunk 0..31
    const int b = blockIdx.x / 48;
    const int e = blockIdx.x % 48;

    const float Ac = -__expf(A_log[e*NST + n]);
    const float Dc = Dw[e];

    const size_t eb = ((size_t)b*48 + e)*LL + c*SCS;
    const float4* dp = (const float4*)(dT + eb);
    const float4* xp = (const float4*)(xT + eb);
    const float4* bp4 = (const float4*)Bi4 + ((size_t)b*(LL/4) + c*(SCS/4))*32 + n;
    const float4* cp4 = (const float4*)Ci4 + ((size_t)b*(LL/4) + c*(SCS/4))*32 + n;

    float h = 0.f, S = 0.f;

    // ---- phase A ----
    #pragma unroll
    for (int q = 0; q < SCS/4; ++q) {
        float4 d4 = dp[q], x4 = xp[q];
        float4 b4 = bp4[q*32];
        float4 c4 = cp4[q*32];
        float p0, p1, p2, p3;
        h = fmaf(__expf(d4.x*Ac), h, d4.x*x4.x*b4.x); p0 = h*c4.x;
        h = fmaf(__expf(d4.y*Ac), h, d4.y*x4.y*b4.y); p1 = h*c4.y;
        h = fmaf(__expf(d4.z*Ac), h, d4.z*x4.z*b4.z); p2 = h*c4.z;
        h = fmaf(__expf(d4.w*Ac), h, d4.w*x4.w*b4.w); p3 = h*c4.w;
        float s0 = S + d4.x, s1 = s0 + d4.y, s2 = s1 + d4.z, s3 = s2 + d4.w;
        S = s3;
        if (n == 0) *(float4*)&sS[c][4*q] = make_float4(s0, s1, s2, s3);
        float q0 = p0 + __shfl_xor(p0, 16);
        float q1 = p1 + __shfl_xor(p1, 16);
        float q2 = p2 + __shfl_xor(p2, 16);
        float q3 = p3 + __shfl_xor(p3, 16);
        float m01 = (n & 16) ? q1 : q0;
        float m23 = (n & 16) ? q3 : q2;
        m01 += __shfl_xor(m01, 8);
        m23 += __shfl_xor(m23, 8);
        float mm = (n & 8) ? m23 : m01;
        mm += __shfl_xor(mm, 4);
        mm += __shfl_xor(mm, 2);
        mm += __shfl_xor(mm, 1);
        if ((n & 7) == 0) {
            int vidx = ((n >> 4) & 1) | (((n >> 3) & 1) << 1);
            float xv = (vidx & 2) ? ((vidx & 1) ? x4.w : x4.z)
                                  : ((vidx & 1) ? x4.y : x4.x);
            sYL[c][4*q + vidx] = fmaf(Dc, xv, mm);
        }
    }
    sPH[c][n] = make_float2(__expf(Ac*S), h);
    __syncthreads();

    // ---- phase B: carry scan over 32 chunks (one 32-lane unit, batched) ----
    if (tid < 32) {
        float acc = 0.f;
        #pragma unroll
        for (int batch = 0; batch < 4; ++batch) {
            float2 v[8];
            #pragma unroll
            for (int k = 0; k < 8; ++k) v[k] = sPH[batch*8+k][tid];
            #pragma unroll
            for (int k = 0; k < 8; ++k) {
                sACa[batch*8+k][tid] = make_float2(Ac, acc);
                acc = fmaf(v[k].x, acc, v[k].y);
            }
        }
    }
    __syncthreads();

    // ---- phase C: thread = (chunk, t); coalesced CT reads ----
    {
        const int c2 = tid >> 5;
        const int t = tid & 31;
        const float St = sS[c2][t];
        const float yl = sYL[c2][t];
        const float* ctp = CT + (size_t)b*32*LL + c2*SCS + t;
        float corr = 0.f;
        #pragma unroll
        for (int n2 = 0; n2 < 32; ++n2) {
            float2 w = sACa[c2][n2];
            corr = fmaf(ctp[(size_t)n2*LL] * __expf(w.x*St), w.y, corr);
        }
        const size_t o = ((size_t)b*48 + e)*LL + c2*SCS + t;
        ygT[o] = (yl + corr) * zT[o];
    }
}

// ---- head ----
__global__ __launch_bounds__(1024) void head_kernel(
    const float* __restrict__ ygT,
    const float* __restrict__ fcw, const float* __restrict__ fcb,
    const float* __restrict__ clw, const float* __restrict__ clb,
    const float* __restrict__ rgw, const float* __restrict__ rgb,
    float* __restrict__ out)
{
    __shared__ float s_h[BB*48];
    __shared__ float s_f[BB*48];
    const int tid = threadIdx.x;
    const int b = tid >> 6, j = tid & 63;
    if (j < 48) s_h[b*48+j] = ygT[((size_t)b*48 + j)*LL + (LL-1)];
    __syncthreads();
    if (j < 48) {
        float acc = fcb[j];
        for (int k = 0; k < 48; ++k) acc += s_h[b*48+k]*fcw[k*48+j];
        s_f[b*48+j] = fmaxf(acc, 0.f);
    }
    __syncthreads();
    if (j < NCLS) {
        float acc = clb[j];
        for (int k = 0; k < 48; ++k) acc += s_f[b*48+k]*clw[k*NCLS+j];
        out[b*NCLS + j] = acc;
    }
    if (j == NCLS) {
        float acc = rgb[0];
        for (int k = 0; k < 48; ++k) acc += s_f[b*48+k]*rgw[k];
        out[BB*NCLS + b] = acc;
    }
}

extern "C" void kernel_launch(void* const* d_in, const int* in_sizes, int n_in,
                              void* d_out, int out_size, void* d_ws, size_t ws_size,
                              hipStream_t stream)
{
    const float* x     = (const float*)d_in[0];
    const float* ipw   = (const float*)d_in[1];
    const float* cw    = (const float*)d_in[2];
    const float* cb    = (const float*)d_in[3];
    const float* xpw   = (const float*)d_in[4];
    const float* dtw   = (const float*)d_in[5];
    const float* dtb   = (const float*)d_in[6];
    const float* A_log = (const float*)d_in[7];
    const float* Dw    = (const float*)d_in[8];
    const float* nw    = (const float*)d_in[9];
    const float* opw   = (const float*)d_in[10];
    const float* fcw   = (const float*)d_in[11];
    const float* fcb   = (const float*)d_in[12];
    const float* clw   = (const float*)d_in[13];
    const float* clb   = (const float*)d_in[14];
    const float* rgw   = (const float*)d_in[15];
    const float* rgb   = (const float*)d_in[16];
    float* out = (float*)d_out;

    float* ws = (float*)d_ws;
    const size_t BL = (size_t)BB*LL;
    float* xT  = ws;
    float* zT  = xT  + BL*48;
    float* dT  = zT  + BL*48;
    float* Bi4 = dT  + BL*48;
    float* Ci4 = Bi4 + BL*32;
    float* CT  = Ci4 + BL*32;
    float* ygT = CT  + BL*32;

    const dim3 preGrid(BB*64), preBlk(256);
    const dim3 scanGrid(BB*48), scanBlk(1024);

    // ---- layer 0 ----
    pre_kernel<0><<<preGrid, preBlk, 0, stream>>>(
        x, nullptr, nullptr, ipw, nw, cw, cb, xpw, dtw, dtb,
        xT, zT, dT, Bi4, Ci4, CT);
    scan_fused<<<scanGrid, scanBlk, 0, stream>>>(
        dT, xT, zT, Bi4, Ci4, CT, A_log, Dw, ygT);

    // ---- layer 1 ----
    pre_kernel<1><<<preGrid, preBlk, 0, stream>>>(
        x, ygT, opw, ipw + 576, nw + 6, cw + 768, cb + 48,
        xpw + 3120, dtw + 48, dtb + 48,
        xT, zT, dT, Bi4, Ci4, CT);
    scan_fused<<<scanGrid, scanBlk, 0, stream>>>(
        dT, xT, zT, Bi4, Ci4, CT, A_log + 1536, Dw + 48, ygT);

    head_kernel<<<dim3(1), dim3(1024), 0, stream>>>(
        ygT, fcw, fcb, clw, clb, rgw, rgb, out);
}

// Round 13
// 168.576 us; speedup vs baseline: 1.9015x; 1.0528x over previous
//
#include <hip/hip_runtime.h>
#include <math.h>

#define BB 16
#define LL 1024
#define DM 6
#define NST 32
#define DCONVK 16
#define NCLS 4
#define CH 32    // positions per pre-kernel block
#define HALO 15
#define ROWS (CH + HALO)   // 47
#define PBT 512            // pre block threads
#define SNC 32   // scan chunks per block
#define SCS 32   // scan chunk length (SNC*SCS = LL)

__device__ __forceinline__ float softplus_f(float x) {
    return fmaxf(x, 0.f) + log1pf(expf(-fabsf(x)));
}
__device__ __forceinline__ float silu_f(float x) {
    return x / (1.f + __expf(-x));
}

// Fused: [MODE0: rmsnorm(x)] / [MODE1: ygT@opw + x residual -> rmsnorm]
//        -> in_proj -> split -> causal dwconv+silu -> x_proj -> softplus(delta)
// Outputs: xT/dT (B,48,L); zT = silu(z) (B,48,L);
//          Bi4/Ci4 packed (B,L/4,32,4); CT (B,32,L).
template<int MODE>
__global__ __launch_bounds__(PBT, 4) void pre_kernel(
    const float* __restrict__ hin,     // x (B,L,6): MODE0 input / MODE1 residual
    const float* __restrict__ ygT_in,  // MODE1: (B,48,L)
    const float* __restrict__ opw,     // MODE1: (48,6)
    const float* __restrict__ ipw,     // (6,96)
    const float* __restrict__ nw,      // (6)
    const float* __restrict__ cw,      // (48,16)
    const float* __restrict__ cb,      // (48)
    const float* __restrict__ xpw,     // (48,65)
    const float* __restrict__ dtw,     // (48)
    const float* __restrict__ dtb,     // (48)
    float* __restrict__ xT,            // (B,48,L)
    float* __restrict__ zT,            // (B,48,L)  silu-applied
    float* __restrict__ dT,            // (B,48,L)
    float* __restrict__ Bi4,           // (B,L/4,32,4)
    float* __restrict__ Ci4,           // (B,L/4,32,4)
    float* __restrict__ CT)            // (B,32,L)
{
    __shared__ float s_ipw[6*96];
    __shared__ float s_nw[6];
    __shared__ float s_cw[48*DCONVK];
    __shared__ float s_cb[48];
    __shared__ float s_xpw[48*65];
    __shared__ float s_dtw[48];
    __shared__ float s_dtb[48];
    __shared__ float s_opw[48*6];
    __shared__ float s_pp[ROWS*8*6];
    __shared__ float s_u[ROWS*7];
    __shared__ float s_raw[ROWS*49];
    __shared__ float s_xsT[48*CH];        // [c][p] channel-major
    __shared__ float s_bc[64*(CH+1)];     // [col][p] for B/C transpose-out
    __shared__ float s_dlt[CH];

    const int tid = threadIdx.x;
    const int b  = blockIdx.x >> 5;
    const int l0 = (blockIdx.x & 31) * CH;

    for (int i = tid; i < 6*96; i += PBT) s_ipw[i] = ipw[i];
    if (tid < 6) s_nw[tid] = nw[tid];
    for (int i = tid; i < 48*DCONVK; i += PBT) s_cw[i] = cw[i];
    if (tid < 48) s_cb[tid] = cb[tid];
    for (int i = tid; i < 48*65; i += PBT) s_xpw[i] = xpw[i];
    if (tid < 48) { s_dtw[tid] = dtw[tid]; s_dtb[tid] = dtb[tid]; }
    if (MODE == 1) for (int i = tid; i < 48*6; i += PBT) s_opw[i] = opw[i];
    __syncthreads();

    // ---- phase 0: produce s_u (normalized rows l0-15 .. l0+CH-1) ----
    if (MODE == 0) {
        if (tid < ROWS) {
            int l = l0 - HALO + tid;
            float u[DM];
            if (l >= 0) {
                float ss = 0.f;
                const float* hp = hin + ((size_t)b*LL + l)*DM;
                #pragma unroll
                for (int d = 0; d < DM; ++d) { u[d] = hp[d]; ss += u[d]*u[d]; }
                float sc = rsqrtf(ss * (1.f/DM) + 1e-5f);
                #pragma unroll
                for (int d = 0; d < DM; ++d) u[d] *= sc * s_nw[d];
            } else {
                #pragma unroll
                for (int d = 0; d < DM; ++d) u[d] = 0.f;
            }
            #pragma unroll
            for (int d = 0; d < DM; ++d) s_u[tid*7+d] = u[d];
        }
        __syncthreads();
    } else {
        // proj0 fused: ygT^T @ opw (8 e-groups of 6), + residual, rmsnorm
        const int g = tid >> 6, t = tid & 63;
        if (t < ROWS) {
            int l = l0 - HALO + t;
            float pacc[DM] = {0,0,0,0,0,0};
            if (l >= 0) {
                for (int e = g*6; e < g*6 + 6; ++e) {
                    float v = ygT_in[((size_t)b*48 + e)*LL + l];
                    #pragma unroll
                    for (int d = 0; d < DM; ++d) pacc[d] += v * s_opw[e*DM+d];
                }
            }
            #pragma unroll
            for (int d = 0; d < DM; ++d) s_pp[(t*8+g)*DM+d] = pacc[d];
        }
        __syncthreads();
        if (tid < ROWS) {
            int l = l0 - HALO + tid;
            float u[DM];
            if (l >= 0) {
                const float* xr = hin + ((size_t)b*LL + l)*DM;
                float ss = 0.f;
                #pragma unroll
                for (int d = 0; d < DM; ++d) {
                    float hv = xr[d];
                    #pragma unroll
                    for (int g2 = 0; g2 < 8; ++g2) hv += s_pp[(tid*8+g2)*DM+d];
                    u[d] = hv; ss += hv*hv;
                }
                float sc = rsqrtf(ss * (1.f/DM) + 1e-5f);
                #pragma unroll
                for (int d = 0; d < DM; ++d) u[d] *= sc * s_nw[d];
            } else {
                #pragma unroll
                for (int d = 0; d < DM; ++d) u[d] = 0.f;
            }
            #pragma unroll
            for (int d = 0; d < DM; ++d) s_u[tid*7+d] = u[d];
        }
        __syncthreads();
    }

    // ---- phase 1: in_proj (96 cols x ROWS rows); z gets silu applied ----
    for (int i = tid; i < 96*ROWS; i += PBT) {
        int j = i / ROWS, t = i - j*ROWS;
        float acc = 0.f;
        #pragma unroll
        for (int d = 0; d < DM; ++d) acc += s_u[t*7+d]*s_ipw[d*96+j];
        if (j < 48) s_raw[t*49+j] = acc;
        else if (t >= HALO)
            zT[((size_t)b*48 + (j-48))*LL + (l0 - HALO + t)] = silu_f(acc);
    }
    __syncthreads();

    // ---- phase 2: depthwise causal conv (K=16) + silu ----
    for (int o = tid; o < 48*CH; o += PBT) {
        int c = o >> 5, p = o & 31;
        float acc = s_cb[c];
        #pragma unroll
        for (int k = 0; k < DCONVK; ++k)
            acc += s_raw[(p+k)*49 + c] * s_cw[c*DCONVK + k];
        float v = silu_f(acc);
        s_xsT[c*CH + p] = v;
        xT[((size_t)b*48 + c)*LL + l0 + p] = v;
    }
    __syncthreads();

    // ---- phase 3: x_proj. thread = (col j:64, pos-group g:8), 4 pos each ----
    {
        const int j = tid >> 3, g = tid & 7;
        float a0=0,a1=0,a2=0,a3=0;
        for (int e = 0; e < 48; ++e) {
            float4 xv = *(const float4*)&s_xsT[e*CH + 4*g];
            float w = s_xpw[e*65 + 1 + j];
            a0 = fmaf(xv.x, w, a0); a1 = fmaf(xv.y, w, a1);
            a2 = fmaf(xv.z, w, a2); a3 = fmaf(xv.w, w, a3);
        }
        s_bc[j*(CH+1) + 4*g+0] = a0; s_bc[j*(CH+1) + 4*g+1] = a1;
        s_bc[j*(CH+1) + 4*g+2] = a2; s_bc[j*(CH+1) + 4*g+3] = a3;
    }
    if (tid < CH) {
        float acc = 0.f;
        for (int e = 0; e < 48; ++e) acc += s_xsT[e*CH + tid]*s_xpw[e*65];
        s_dlt[tid] = acc;
    }
    __syncthreads();

    // ---- phase 3b: write B/C packed (B,L/4,32,4) + C transposed ----
    {   // 2*(CH/4)*32 = 512 items, exactly one per thread
        int o = tid;
        int which = o >> 8;                 // 0:B 1:C
        int lg = (o >> 5) & (CH/4 - 1), n = o & 31;
        const float* src = &s_bc[(which*32 + n)*(CH+1) + 4*lg];
        float4 v = make_float4(src[0], src[1], src[2], src[3]);
        float4* dst = (float4*)(which ? Ci4 : Bi4);
        dst[((size_t)b*(LL/4) + (l0/4 + lg))*32 + n] = v;
    }
    for (int o = tid; o < 32*CH; o += PBT) {
        int n = o >> 5, l = o & 31;
        CT[((size_t)b*32 + n)*LL + l0 + l] = s_bc[(32+n)*(CH+1) + l];
    }

    // ---- phase 4: delta = softplus(dlt*dt_w + dt_b), transposed write ----
    for (int o = tid; o < 48*CH; o += PBT) {
        int e = o >> 5, p = o & 31;
        float xv = s_dlt[p]*s_dtw[e] + s_dtb[e];
        dT[((size_t)b*48 + e)*LL + l0 + p] = softplus_f(xv);
    }
}

// ---- fused selective scan (unchanged from R12 best) ----
__global__ __launch_bounds__(1024, 8) void scan_fused(
    const float* __restrict__ dT,
    const float* __restrict__ xT,
    const float* __restrict__ zT,     // silu(z)
    const float* __restrict__ Bi4,    // (B,L/4,32,4)
    const float* __restrict__ Ci4,    // (B,L/4,32,4)
    const float* __restrict__ CT,     // (B,32,L)
    const float* __restrict__ A_log,  // (48,32)
    const float* __restrict__ Dw,     // (48)
    float* __restrict__ ygT)          // (B,48,L)
{
    __shared__ float2 sPH[SNC][32];    // (P_chunk, h_end)
    __shared__ float2 sACa[SNC][32];   // (Ac, carry)
    __shared__ float  sYL[SNC][SCS];   // local y (incl. D*x)
    __shared__ float  sS [SNC][SCS];   // delta prefix within chunk

    const int tid = threadIdx.x;
    const int lane = tid & 63;
    const int ch = lane >> 5, n = lane & 31;
    const int c = ((tid >> 6) << 1) | ch;   // chunk 0..31
    const int b = blockIdx.x / 48;
    const int e = blockIdx.x % 48;

    const float Ac = -__expf(A_log[e*NST + n]);
    const float Dc = Dw[e];

    const size_t eb = ((size_t)b*48 + e)*LL + c*SCS;
    const float4* dp = (const float4*)(dT + eb);
    const float4* xp = (const float4*)(xT + eb);
    const float4* bp4 = (const float4*)Bi4 + ((size_t)b*(LL/4) + c*(SCS/4))*32 + n;
    const float4* cp4 = (const float4*)Ci4 + ((size_t)b*(LL/4) + c*(SCS/4))*32 + n;

    float h = 0.f, S = 0.f;

    // ---- phase A ----
    #pragma unroll
    for (int q = 0; q < SCS/4; ++q) {
        float4 d4 = dp[q], x4 = xp[q];
        float4 b4 = bp4[q*32];
        float4 c4 = cp4[q*32];
        float p0, p1, p2, p3;
        h = fmaf(__expf(d4.x*Ac), h, d4.x*x4.x*b4.x); p0 = h*c4.x;
        h = fmaf(__expf(d4.y*Ac), h, d4.y*x4.y*b4.y); p1 = h*c4.y;
        h = fmaf(__expf(d4.z*Ac), h, d4.z*x4.z*b4.z); p2 = h*c4.z;
        h = fmaf(__expf(d4.w*Ac), h, d4.w*x4.w*b4.w); p3 = h*c4.w;
        float s0 = S + d4.x, s1 = s0 + d4.y, s2 = s1 + d4.z, s3 = s2 + d4.w;
        S = s3;
        if (n == 0) *(float4*)&sS[c][4*q] = make_float4(s0, s1, s2, s3);
        float q0 = p0 + __shfl_xor(p0, 16);
        float q1 = p1 + __shfl_xor(p1, 16);
        float q2 = p2 + __shfl_xor(p2, 16);
        float q3 = p3 + __shfl_xor(p3, 16);
        float m01 = (n & 16) ? q1 : q0;
        float m23 = (n & 16) ? q3 : q2;
        m01 += __shfl_xor(m01, 8);
        m23 += __shfl_xor(m23, 8);
        float mm = (n & 8) ? m23 : m01;
        mm += __shfl_xor(mm, 4);
        mm += __shfl_xor(mm, 2);
        mm += __shfl_xor(mm, 1);
        if ((n & 7) == 0) {
            int vidx = ((n >> 4) & 1) | (((n >> 3) & 1) << 1);
            float xv = (vidx & 2) ? ((vidx & 1) ? x4.w : x4.z)
                                  : ((vidx & 1) ? x4.y : x4.x);
            sYL[c][4*q + vidx] = fmaf(Dc, xv, mm);
        }
    }
    sPH[c][n] = make_float2(__expf(Ac*S), h);
    __syncthreads();

    // ---- phase B: carry scan over 32 chunks (one 32-lane unit, batched) ----
    if (tid < 32) {
        float acc = 0.f;
        #pragma unroll
        for (int batch = 0; batch < 4; ++batch) {
            float2 v[8];
            #pragma unroll
            for (int k = 0; k < 8; ++k) v[k] = sPH[batch*8+k][tid];
            #pragma unroll
            for (int k = 0; k < 8; ++k) {
                sACa[batch*8+k][tid] = make_float2(Ac, acc);
                acc = fmaf(v[k].x, acc, v[k].y);
            }
        }
    }
    __syncthreads();

    // ---- phase C: thread = (chunk, t); coalesced CT reads ----
    {
        const int c2 = tid >> 5;
        const int t = tid & 31;
        const float St = sS[c2][t];
        const float yl = sYL[c2][t];
        const float* ctp = CT + (size_t)b*32*LL + c2*SCS + t;
        float corr = 0.f;
        #pragma unroll
        for (int n2 = 0; n2 < 32; ++n2) {
            float2 w = sACa[c2][n2];
            corr = fmaf(ctp[(size_t)n2*LL] * __expf(w.x*St), w.y, corr);
        }
        const size_t o = ((size_t)b*48 + e)*LL + c2*SCS + t;
        ygT[o] = (yl + corr) * zT[o];
    }
}

// ---- head ----
__global__ __launch_bounds__(1024) void head_kernel(
    const float* __restrict__ ygT,
    const float* __restrict__ fcw, const float* __restrict__ fcb,
    const float* __restrict__ clw, const float* __restrict__ clb,
    const float* __restrict__ rgw, const float* __restrict__ rgb,
    float* __restrict__ out)
{
    __shared__ float s_h[BB*48];
    __shared__ float s_f[BB*48];
    const int tid = threadIdx.x;
    const int b = tid >> 6, j = tid & 63;
    if (j < 48) s_h[b*48+j] = ygT[((size_t)b*48 + j)*LL + (LL-1)];
    __syncthreads();
    if (j < 48) {
        float acc = fcb[j];
        for (int k = 0; k < 48; ++k) acc += s_h[b*48+k]*fcw[k*48+j];
        s_f[b*48+j] = fmaxf(acc, 0.f);
    }
    __syncthreads();
    if (j < NCLS) {
        float acc = clb[j];
        for (int k = 0; k < 48; ++k) acc += s_f[b*48+k]*clw[k*NCLS+j];
        out[b*NCLS + j] = acc;
    }
    if (j == NCLS) {
        float acc = rgb[0];
        for (int k = 0; k < 48; ++k) acc += s_f[b*48+k]*rgw[k];
        out[BB*NCLS + b] = acc;
    }
}

extern "C" void kernel_launch(void* const* d_in, const int* in_sizes, int n_in,
                              void* d_out, int out_size, void* d_ws, size_t ws_size,
                              hipStream_t stream)
{
    const float* x     = (const float*)d_in[0];
    const float* ipw   = (const float*)d_in[1];
    const float* cw    = (const float*)d_in[2];
    const float* cb    = (const float*)d_in[3];
    const float* xpw   = (const float*)d_in[4];
    const float* dtw   = (const float*)d_in[5];
    const float* dtb   = (const float*)d_in[6];
    const float* A_log = (const float*)d_in[7];
    const float* Dw    = (const float*)d_in[8];
    const float* nw    = (const float*)d_in[9];
    const float* opw   = (const float*)d_in[10];
    const float* fcw   = (const float*)d_in[11];
    const float* fcb   = (const float*)d_in[12];
    const float* clw   = (const float*)d_in[13];
    const float* clb   = (const float*)d_in[14];
    const float* rgw   = (const float*)d_in[15];
    const float* rgb   = (const float*)d_in[16];
    float* out = (float*)d_out;

    float* ws = (float*)d_ws;
    const size_t BL = (size_t)BB*LL;
    float* xT  = ws;
    float* zT  = xT  + BL*48;
    float* dT  = zT  + BL*48;
    float* Bi4 = dT  + BL*48;
    float* Ci4 = Bi4 + BL*32;
    float* CT  = Ci4 + BL*32;
    float* ygT = CT  + BL*32;

    const dim3 preGrid(BB*32), preBlk(PBT);
    const dim3 scanGrid(BB*48), scanBlk(1024);

    // ---- layer 0 ----
    pre_kernel<0><<<preGrid, preBlk, 0, stream>>>(
        x, nullptr, nullptr, ipw, nw, cw, cb, xpw, dtw, dtb,
        xT, zT, dT, Bi4, Ci4, CT);
    scan_fused<<<scanGrid, scanBlk, 0, stream>>>(
        dT, xT, zT, Bi4, Ci4, CT, A_log, Dw, ygT);

    // ---- layer 1 ----
    pre_kernel<1><<<preGrid, preBlk, 0, stream>>>(
        x, ygT, opw, ipw + 576, nw + 6, cw + 768, cb + 48,
        xpw + 3120, dtw + 48, dtb + 48,
        xT, zT, dT, Bi4, Ci4, CT);
    scan_fused<<<scanGrid, scanBlk, 0, stream>>>(
        dT, xT, zT, Bi4, Ci4, CT, A_log + 1536, Dw + 48, ygT);

    head_kernel<<<dim3(1), dim3(1024), 0, stream>>>(
        ygT, fcw, fcb, clw, clb, rgw, rgb, out);
}

// Round 14
// 166.844 us; speedup vs baseline: 1.9212x; 1.0104x over previous
//
#include <hip/hip_runtime.h>
#include <math.h>

#define BB 16
#define LL 1024
#define DM 6
#define NST 32
#define DCONVK 16
#define NCLS 4
#define CH 64    // positions per pre-kernel block
#define HALO 15
#define ROWS (CH + HALO)   // 79
#define PBT 1024           // pre block threads
#define SNC 32   // scan chunks per block
#define SCS 32   // scan chunk length (SNC*SCS = LL)

__device__ __forceinline__ float softplus_f(float x) {
    return fmaxf(x, 0.f) + log1pf(expf(-fabsf(x)));
}
__device__ __forceinline__ float silu_f(float x) {
    return x / (1.f + __expf(-x));
}

// Fused: [MODE0: rmsnorm(x)] / [MODE1: ygT@opw + x residual -> rmsnorm]
//        -> in_proj -> split -> causal dwconv+silu -> x_proj -> softplus(delta)
// Outputs: xT/dT (B,48,L); zT = silu(z) (B,48,L);
//          Bi4/Ci4 packed (B,L/4,32,4); CT (B,32,L).
// LDS: s_pp / s_raw / s_bc are temporally disjoint -> unioned in s_un.
template<int MODE>
__global__ __launch_bounds__(PBT) void pre_kernel(
    const float* __restrict__ hin,     // x (B,L,6): MODE0 input / MODE1 residual
    const float* __restrict__ ygT_in,  // MODE1: (B,48,L)
    const float* __restrict__ opw,     // MODE1: (48,6)
    const float* __restrict__ ipw,     // (6,96)
    const float* __restrict__ nw,      // (6)
    const float* __restrict__ cw,      // (48,16)
    const float* __restrict__ cb,      // (48)
    const float* __restrict__ xpw,     // (48,65)
    const float* __restrict__ dtw,     // (48)
    const float* __restrict__ dtb,     // (48)
    float* __restrict__ xT,            // (B,48,L)
    float* __restrict__ zT,            // (B,48,L)  silu-applied
    float* __restrict__ dT,            // (B,48,L)
    float* __restrict__ Bi4,           // (B,L/4,32,4)
    float* __restrict__ Ci4,           // (B,L/4,32,4)
    float* __restrict__ CT)            // (B,32,L)
{
    __shared__ float s_un[ROWS*49 > 64*(CH+1) ? ROWS*49 : 64*(CH+1)];
    __shared__ float s_ipw[6*96];
    __shared__ float s_nw[8];
    __shared__ float s_cw[48*DCONVK];
    __shared__ float s_cb[48];
    __shared__ float s_xpw[48*65];
    __shared__ float s_dtw[48];
    __shared__ float s_dtb[48];
    __shared__ float s_opw[48*6];
    __shared__ float s_u[ROWS*7];
    __shared__ float s_xsT[48*CH];        // [c][p] channel-major
    __shared__ float s_dlt[CH];

    float* s_pp  = s_un;   // MODE1 phase 0: (ROWS,8,6)
    float* s_raw = s_un;   // phase 1-2: (ROWS,49)
    float* s_bc  = s_un;   // phase 3-3b: (64, CH+1)

    const int tid = threadIdx.x;
    const int b  = blockIdx.x >> 4;
    const int l0 = (blockIdx.x & 15) * CH;

    for (int i = tid; i < 6*96; i += PBT) s_ipw[i] = ipw[i];
    if (tid < 6) s_nw[tid] = nw[tid];
    if (tid < 48*DCONVK) s_cw[tid] = cw[tid];
    if (tid < 48) s_cb[tid] = cb[tid];
    for (int i = tid; i < 48*65; i += PBT) s_xpw[i] = xpw[i];
    if (tid < 48) { s_dtw[tid] = dtw[tid]; s_dtb[tid] = dtb[tid]; }
    if (MODE == 1) { if (tid < 48*6) s_opw[tid] = opw[tid]; }
    __syncthreads();

    // ---- phase 0: produce s_u (normalized rows l0-15 .. l0+CH-1) ----
    if (MODE == 0) {
        if (tid < ROWS) {
            int l = l0 - HALO + tid;
            float u[DM];
            if (l >= 0) {
                float ss = 0.f;
                const float* hp = hin + ((size_t)b*LL + l)*DM;
                #pragma unroll
                for (int d = 0; d < DM; ++d) { u[d] = hp[d]; ss += u[d]*u[d]; }
                float sc = rsqrtf(ss * (1.f/DM) + 1e-5f);
                #pragma unroll
                for (int d = 0; d < DM; ++d) u[d] *= sc * s_nw[d];
            } else {
                #pragma unroll
                for (int d = 0; d < DM; ++d) u[d] = 0.f;
            }
            #pragma unroll
            for (int d = 0; d < DM; ++d) s_u[tid*7+d] = u[d];
        }
        __syncthreads();
    } else {
        // proj0 fused: ygT^T @ opw (8 e-groups of 6), + residual, rmsnorm
        const int g = tid >> 7, t = tid & 127;   // 8 groups x 128 rows
        if (t < ROWS) {
            int l = l0 - HALO + t;
            float pacc[DM] = {0,0,0,0,0,0};
            if (l >= 0) {
                for (int e = g*6; e < g*6 + 6; ++e) {
                    float v = ygT_in[((size_t)b*48 + e)*LL + l];
                    #pragma unroll
                    for (int d = 0; d < DM; ++d) pacc[d] += v * s_opw[e*DM+d];
                }
            }
            #pragma unroll
            for (int d = 0; d < DM; ++d) s_pp[(t*8+g)*DM+d] = pacc[d];
        }
        __syncthreads();
        float u[DM]; float ss = 0.f;
        if (tid < ROWS) {
            int l = l0 - HALO + tid;
            if (l >= 0) {
                const float* xr = hin + ((size_t)b*LL + l)*DM;
                #pragma unroll
                for (int d = 0; d < DM; ++d) {
                    float hv = xr[d];
                    #pragma unroll
                    for (int g2 = 0; g2 < 8; ++g2) hv += s_pp[(tid*8+g2)*DM+d];
                    u[d] = hv; ss += hv*hv;
                }
                float sc = rsqrtf(ss * (1.f/DM) + 1e-5f);
                #pragma unroll
                for (int d = 0; d < DM; ++d) u[d] *= sc * s_nw[d];
            } else {
                #pragma unroll
                for (int d = 0; d < DM; ++d) u[d] = 0.f;
            }
        }
        __syncthreads();   // s_pp dead before s_raw written (same memory)
        if (tid < ROWS) {
            #pragma unroll
            for (int d = 0; d < DM; ++d) s_u[tid*7+d] = u[d];
        }
        __syncthreads();
    }

    // ---- phase 1: in_proj (96 cols x ROWS rows); z gets silu applied ----
    for (int i = tid; i < 96*ROWS; i += PBT) {
        int j = i / ROWS, t = i - j*ROWS;
        float acc = 0.f;
        #pragma unroll
        for (int d = 0; d < DM; ++d) acc += s_u[t*7+d]*s_ipw[d*96+j];
        if (j < 48) s_raw[t*49+j] = acc;
        else if (t >= HALO)
            zT[((size_t)b*48 + (j-48))*LL + (l0 - HALO + t)] = silu_f(acc);
    }
    __syncthreads();

    // ---- phase 2: depthwise causal conv (K=16) + silu ----
    for (int o = tid; o < 48*CH; o += PBT) {
        int c = o >> 6, p = o & 63;
        float acc = s_cb[c];
        #pragma unroll
        for (int k = 0; k < DCONVK; ++k)
            acc += s_raw[(p+k)*49 + c] * s_cw[c*DCONVK + k];
        float v = silu_f(acc);
        s_xsT[c*CH + p] = v;
        xT[((size_t)b*48 + c)*LL + l0 + p] = v;
    }
    __syncthreads();   // s_raw dead before s_bc written (same memory)

    // ---- phase 3: x_proj. thread = (col j:64, pos-group g:16), 4 pos each ----
    {
        const int j = tid >> 4, g = tid & 15;
        float a0=0,a1=0,a2=0,a3=0;
        for (int e = 0; e < 48; ++e) {
            float4 xv = *(const float4*)&s_xsT[e*CH + 4*g];
            float w = s_xpw[e*65 + 1 + j];
            a0 = fmaf(xv.x, w, a0); a1 = fmaf(xv.y, w, a1);
            a2 = fmaf(xv.z, w, a2); a3 = fmaf(xv.w, w, a3);
        }
        s_bc[j*(CH+1) + 4*g+0] = a0; s_bc[j*(CH+1) + 4*g+1] = a1;
        s_bc[j*(CH+1) + 4*g+2] = a2; s_bc[j*(CH+1) + 4*g+3] = a3;
    }
    if (tid < CH) {
        float acc = 0.f;
        for (int e = 0; e < 48; ++e) acc += s_xsT[e*CH + tid]*s_xpw[e*65];
        s_dlt[tid] = acc;
    }
    __syncthreads();

    // ---- phase 3b: write B/C packed (B,L/4,32,4) + C transposed ----
    {   // 2*(CH/4)*32 = 1024 items, exactly one per thread
        int o = tid;
        int which = o >> 9;                 // 0:B 1:C
        int lg = (o >> 5) & (CH/4 - 1), n = o & 31;
        const float* src = &s_bc[(which*32 + n)*(CH+1) + 4*lg];
        float4 v = make_float4(src[0], src[1], src[2], src[3]);
        float4* dst = (float4*)(which ? Ci4 : Bi4);
        dst[((size_t)b*(LL/4) + (l0/4 + lg))*32 + n] = v;
    }
    for (int o = tid; o < 32*CH; o += PBT) {
        int n = o >> 6, l = o & 63;
        CT[((size_t)b*32 + n)*LL + l0 + l] = s_bc[(32+n)*(CH+1) + l];
    }

    // ---- phase 4: delta = softplus(dlt*dt_w + dt_b), transposed write ----
    for (int o = tid; o < 48*CH; o += PBT) {
        int e = o >> 6, p = o & 63;
        float xv = s_dlt[p]*s_dtw[e] + s_dtb[e];
        dT[((size_t)b*48 + e)*LL + l0 + p] = softplus_f(xv);
    }
}

// ---- fused selective scan (unchanged from R13 best) ----
__global__ __launch_bounds__(1024, 8) void scan_fused(
    const float* __restrict__ dT,
    const float* __restrict__ xT,
    const float* __restrict__ zT,     // silu(z)
    const float* __restrict__ Bi4,    // (B,L/4,32,4)
    const float* __restrict__ Ci4,    // (B,L/4,32,4)
    const float* __restrict__ CT,     // (B,32,L)
    const float* __restrict__ A_log,  // (48,32)
    const float* __restrict__ Dw,     // (48)
    float* __restrict__ ygT)          // (B,48,L)
{
    __shared__ float2 sPH[SNC][32];    // (P_chunk, h_end)
    __shared__ float2 sACa[SNC][32];   // (Ac, carry)
    __shared__ float  sYL[SNC][SCS];   // local y (incl. D*x)
    __shared__ float  sS [SNC][SCS];   // delta prefix within chunk

    const int tid = threadIdx.x;
    const int lane = tid & 63;
    const int ch = lane >> 5, n = lane & 31;
    const int c = ((tid >> 6) << 1) | ch;   // chunk 0..31
    const int b = blockIdx.x / 48;
    const int e = blockIdx.x % 48;

    const float Ac = -__expf(A_log[e*NST + n]);
    const float Dc = Dw[e];

    const size_t eb = ((size_t)b*48 + e)*LL + c*SCS;
    const float4* dp = (const float4*)(dT + eb);
    const float4* xp = (const float4*)(xT + eb);
    const float4* bp4 = (const float4*)Bi4 + ((size_t)b*(LL/4) + c*(SCS/4))*32 + n;
    const float4* cp4 = (const float4*)Ci4 + ((size_t)b*(LL/4) + c*(SCS/4))*32 + n;

    float h = 0.f, S = 0.f;

    // ---- phase A ----
    #pragma unroll
    for (int q = 0; q < SCS/4; ++q) {
        float4 d4 = dp[q], x4 = xp[q];
        float4 b4 = bp4[q*32];
        float4 c4 = cp4[q*32];
        float p0, p1, p2, p3;
        h = fmaf(__expf(d4.x*Ac), h, d4.x*x4.x*b4.x); p0 = h*c4.x;
        h = fmaf(__expf(d4.y*Ac), h, d4.y*x4.y*b4.y); p1 = h*c4.y;
        h = fmaf(__expf(d4.z*Ac), h, d4.z*x4.z*b4.z); p2 = h*c4.z;
        h = fmaf(__expf(d4.w*Ac), h, d4.w*x4.w*b4.w); p3 = h*c4.w;
        float s0 = S + d4.x, s1 = s0 + d4.y, s2 = s1 + d4.z, s3 = s2 + d4.w;
        S = s3;
        if (n == 0) *(float4*)&sS[c][4*q] = make_float4(s0, s1, s2, s3);
        float q0 = p0 + __shfl_xor(p0, 16);
        float q1 = p1 + __shfl_xor(p1, 16);
        float q2 = p2 + __shfl_xor(p2, 16);
        float q3 = p3 + __shfl_xor(p3, 16);
        float m01 = (n & 16) ? q1 : q0;
        float m23 = (n & 16) ? q3 : q2;
        m01 += __shfl_xor(m01, 8);
        m23 += __shfl_xor(m23, 8);
        float mm = (n & 8) ? m23 : m01;
        mm += __shfl_xor(mm, 4);
        mm += __shfl_xor(mm, 2);
        mm += __shfl_xor(mm, 1);
        if ((n & 7) == 0) {
            int vidx = ((n >> 4) & 1) | (((n >> 3) & 1) << 1);
            float xv = (vidx & 2) ? ((vidx & 1) ? x4.w : x4.z)
                                  : ((vidx & 1) ? x4.y : x4.x);
            sYL[c][4*q + vidx] = fmaf(Dc, xv, mm);
        }
    }
    sPH[c][n] = make_float2(__expf(Ac*S), h);
    __syncthreads();

    // ---- phase B: carry scan over 32 chunks (one 32-lane unit, batched) ----
    if (tid < 32) {
        float acc = 0.f;
        #pragma unroll
        for (int batch = 0; batch < 4; ++batch) {
            float2 v[8];
            #pragma unroll
            for (int k = 0; k < 8; ++k) v[k] = sPH[batch*8+k][tid];
            #pragma unroll
            for (int k = 0; k < 8; ++k) {
                sACa[batch*8+k][tid] = make_float2(Ac, acc);
                acc = fmaf(v[k].x, acc, v[k].y);
            }
        }
    }
    __syncthreads();

    // ---- phase C: thread = (chunk, t); coalesced CT reads ----
    {
        const int c2 = tid >> 5;
        const int t = tid & 31;
        const float St = sS[c2][t];
        const float yl = sYL[c2][t];
        const float* ctp = CT + (size_t)b*32*LL + c2*SCS + t;
        float corr = 0.f;
        #pragma unroll
        for (int n2 = 0; n2 < 32; ++n2) {
            float2 w = sACa[c2][n2];
            corr = fmaf(ctp[(size_t)n2*LL] * __expf(w.x*St), w.y, corr);
        }
        const size_t o = ((size_t)b*48 + e)*LL + c2*SCS + t;
        ygT[o] = (yl + corr) * zT[o];
    }
}

// ---- head ----
__global__ __launch_bounds__(1024) void head_kernel(
    const float* __restrict__ ygT,
    const float* __restrict__ fcw, const float* __restrict__ fcb,
    const float* __restrict__ clw, const float* __restrict__ clb,
    const float* __restrict__ rgw, const float* __restrict__ rgb,
    float* __restrict__ out)
{
    __shared__ float s_h[BB*48];
    __shared__ float s_f[BB*48];
    const int tid = threadIdx.x;
    const int b = tid >> 6, j = tid & 63;
    if (j < 48) s_h[b*48+j] = ygT[((size_t)b*48 + j)*LL + (LL-1)];
    __syncthreads();
    if (j < 48) {
        float acc = fcb[j];
        for (int k = 0; k < 48; ++k) acc += s_h[b*48+k]*fcw[k*48+j];
        s_f[b*48+j] = fmaxf(acc, 0.f);
    }
    __syncthreads();
    if (j < NCLS) {
        float acc = clb[j];
        for (int k = 0; k < 48; ++k) acc += s_f[b*48+k]*clw[k*NCLS+j];
        out[b*NCLS + j] = acc;
    }
    if (j == NCLS) {
        float acc = rgb[0];
        for (int k = 0; k < 48; ++k) acc += s_f[b*48+k]*rgw[k];
        out[BB*NCLS + b] = acc;
    }
}

extern "C" void kernel_launch(void* const* d_in, const int* in_sizes, int n_in,
                              void* d_out, int out_size, void* d_ws, size_t ws_size,
                              hipStream_t stream)
{
    const float* x     = (const float*)d_in[0];
    const float* ipw   = (const float*)d_in[1];
    const float* cw    = (const float*)d_in[2];
    const float* cb    = (const float*)d_in[3];
    const float* xpw   = (const float*)d_in[4];
    const float* dtw   = (const float*)d_in[5];
    const float* dtb   = (const float*)d_in[6];
    const float* A_log = (const float*)d_in[7];
    const float* Dw    = (const float*)d_in[8];
    const float* nw    = (const float*)d_in[9];
    const float* opw   = (const float*)d_in[10];
    const float* fcw   = (const float*)d_in[11];
    const float* fcb   = (const float*)d_in[12];
    const float* clw   = (const float*)d_in[13];
    const float* clb   = (const float*)d_in[14];
    const float* rgw   = (const float*)d_in[15];
    const float* rgb   = (const float*)d_in[16];
    float* out = (float*)d_out;

    float* ws = (float*)d_ws;
    const size_t BL = (size_t)BB*LL;
    float* xT  = ws;
    float* zT  = xT  + BL*48;
    float* dT  = zT  + BL*48;
    float* Bi4 = dT  + BL*48;
    float* Ci4 = Bi4 + BL*32;
    float* CT  = Ci4 + BL*32;
    float* ygT = CT  + BL*32;

    const dim3 preGrid(BB*16), preBlk(PBT);
    const dim3 scanGrid(BB*48), scanBlk(1024);

    // ---- layer 0 ----
    pre_kernel<0><<<preGrid, preBlk, 0, stream>>>(
        x, nullptr, nullptr, ipw, nw, cw, cb, xpw, dtw, dtb,
        xT, zT, dT, Bi4, Ci4, CT);
    scan_fused<<<scanGrid, scanBlk, 0, stream>>>(
        dT, xT, zT, Bi4, Ci4, CT, A_log, Dw, ygT);

    // ---- layer 1 ----
    pre_kernel<1><<<preGrid, preBlk, 0, stream>>>(
        x, ygT, opw, ipw + 576, nw + 6, cw + 768, cb + 48,
        xpw + 3120, dtw + 48, dtb + 48,
        xT, zT, dT, Bi4, Ci4, CT);
    scan_fused<<<scanGrid, scanBlk, 0, stream>>>(
        dT, xT, zT, Bi4, Ci4, CT, A_log + 1536, Dw + 48, ygT);

    head_kernel<<<dim3(1), dim3(1024), 0, stream>>>(
        ygT, fcw, fcb, clw, clb, rgw, rgb, out);
}